// Round 7
// baseline (573.942 us; speedup 1.0000x reference)
//
#include <hip/hip_runtime.h>

#define N_NODES 50000
#define N_EDGES 800000
#define N_FEAT 128
#define N_HID 128
#define N_CLS 40
#define BN_EPS 1e-5f

#define SCAN_BLOCKS ((N_NODES + 255) / 256)  // 196

// ---------------------------------------------------------------------------
// K1: int degree histogram.
// ---------------------------------------------------------------------------
__global__ __launch_bounds__(256) void deg_kernel(const int* __restrict__ dst,
                                                  int* __restrict__ deg_i) {
    int e = blockIdx.x * 256 + threadIdx.x;
    if (e < N_EDGES) atomicAdd(&deg_i[dst[e]], 1);
}

// ---------------------------------------------------------------------------
// Scan A/B/C: row_ptr = exclusive scan of degrees.
// ---------------------------------------------------------------------------
__global__ __launch_bounds__(256) void scanA_kernel(const int* __restrict__ deg_i,
                                                    int* __restrict__ row_ptr,
                                                    int* __restrict__ blk_sum) {
    __shared__ int tmp[256];
    int t = threadIdx.x;
    int i = blockIdx.x * 256 + t;
    int v = (i < N_NODES) ? deg_i[i] : 0;
    tmp[t] = v;
    __syncthreads();
    for (int off = 1; off < 256; off <<= 1) {
        int a = (t >= off) ? tmp[t - off] : 0;
        __syncthreads();
        if (t >= off) tmp[t] += a;
        __syncthreads();
    }
    if (i < N_NODES) row_ptr[i] = tmp[t] - v;
    if (t == 255) blk_sum[blockIdx.x] = tmp[255];
}

__global__ __launch_bounds__(256) void scanB_kernel(const int* __restrict__ blk_sum,
                                                    int* __restrict__ blk_off) {
    __shared__ int tmp[256];
    int t = threadIdx.x;
    int v = (t < SCAN_BLOCKS) ? blk_sum[t] : 0;
    tmp[t] = v;
    __syncthreads();
    for (int off = 1; off < 256; off <<= 1) {
        int a = (t >= off) ? tmp[t - off] : 0;
        __syncthreads();
        if (t >= off) tmp[t] += a;
        __syncthreads();
    }
    if (t < SCAN_BLOCKS) blk_off[t] = tmp[t] - v;
}

__global__ __launch_bounds__(256) void scanC_kernel(int* __restrict__ row_ptr,
                                                    const int* __restrict__ blk_off) {
    int i = blockIdx.x * 256 + threadIdx.x;
    if (i < N_NODES) row_ptr[i] += blk_off[blockIdx.x];
    if (i == 0) row_ptr[N_NODES] = N_EDGES;
}

// ---------------------------------------------------------------------------
// CSR fill.
// ---------------------------------------------------------------------------
__global__ __launch_bounds__(256) void fill_kernel(const int* __restrict__ src,
                                                   const int* __restrict__ dst,
                                                   const int* __restrict__ row_ptr,
                                                   int* __restrict__ cursor,
                                                   int* __restrict__ csr_src) {
    int e = blockIdx.x * 256 + threadIdx.x;
    if (e >= N_EDGES) return;
    int d = dst[e];
    int pos = atomicAdd(&cursor[d], 1);
    csr_src[row_ptr[d] + pos] = src[e];
}

// ---------------------------------------------------------------------------
// Weight transpose to k-major:
//   WtA[k][n] 256x128: k<128 -> W1l[n][k]; else W1r[n][k-128]
//   WtB[k][n] 128x80 : n<40 -> W2l[n][k]; else W2r[n-40][k]
// ---------------------------------------------------------------------------
__global__ __launch_bounds__(256) void transposeW_kernel(
    const float* __restrict__ W1l, const float* __restrict__ W1r,
    const float* __restrict__ W2l, const float* __restrict__ W2r,
    float* __restrict__ WtA, float* __restrict__ WtB) {
    int i = blockIdx.x * 256 + threadIdx.x;
    if (i < 256 * 128) {
        int k = i >> 7, n = i & 127;
        WtA[i] = (k < 128) ? W1l[n * 128 + k] : W1r[n * 128 + (k - 128)];
    } else {
        int j = i - 256 * 128;
        if (j < 128 * 80) {
            int k = j / 80, n = j % 80;
            WtB[j] = (n < 40) ? W2l[n * 128 + k] : W2r[(n - 40) * 128 + k];
        }
    }
}

// ---------------------------------------------------------------------------
// Gather-mean layer 1: wave per node; 2 edges per iter (one per half-wave),
// float4 per lane, 3x unrolled -> 6 edges in flight. Folds inv_deg (mean).
// ---------------------------------------------------------------------------
__global__ __launch_bounds__(256) void gather1_kernel(const int* __restrict__ csr_src,
                                                      const int* __restrict__ row_ptr,
                                                      const float* __restrict__ x,
                                                      float* __restrict__ agg1n) {
    int gid = __builtin_amdgcn_readfirstlane(blockIdx.x * 4 + (threadIdx.x >> 6));
    if (gid >= N_NODES) return;
    int lane = threadIdx.x & 63;
    int half = lane >> 5;
    int li = lane & 31;
    int beg = row_ptr[gid], end = row_ptr[gid + 1];
    const float4* x4 = (const float4*)x;
    float4 acc = {0.f, 0.f, 0.f, 0.f};
    int e = beg + half;
    for (; e + 4 < end; e += 6) {
        int s0 = csr_src[e], s1 = csr_src[e + 2], s2 = csr_src[e + 4];
        float4 v0 = x4[(size_t)s0 * 32 + li];
        float4 v1 = x4[(size_t)s1 * 32 + li];
        float4 v2 = x4[(size_t)s2 * 32 + li];
        acc.x += v0.x + v1.x + v2.x;
        acc.y += v0.y + v1.y + v2.y;
        acc.z += v0.z + v1.z + v2.z;
        acc.w += v0.w + v1.w + v2.w;
    }
    for (; e < end; e += 2) {
        int s = csr_src[e];
        float4 v = x4[(size_t)s * 32 + li];
        acc.x += v.x; acc.y += v.y; acc.z += v.z; acc.w += v.w;
    }
    float4 o;
    o.x = __shfl(acc.x, lane ^ 32);
    o.y = __shfl(acc.y, lane ^ 32);
    o.z = __shfl(acc.z, lane ^ 32);
    o.w = __shfl(acc.w, lane ^ 32);
    if (half == 0) {
        float inv = 1.0f / fmaxf((float)(end - beg), 1.0f);
        float4 r;
        r.x = (acc.x + o.x) * inv;
        r.y = (acc.y + o.y) * inv;
        r.z = (acc.z + o.z) * inv;
        r.w = (acc.w + o.w) * inv;
        ((float4*)agg1n)[(size_t)gid * 32 + li] = r;
    }
}

// ---------------------------------------------------------------------------
// GEMM1: h = BN(ReLU(agg1n @ W1l^T + b1 + x @ W1r^T))
// 64 rows x 128 cols per block; 4 waves x 32-col slice (acc[32]).
// A staged once in LDS [64][129]. Weights: lane-uniform global_load_dwordx4
// (opaque-zero VGPR offset forces VMEM) -> weight stream pipelines on vmcnt,
// independent of the A ds_read lgkmcnt -- removes the R6 SMEM/DS
// shared-lgkmcnt serialization. Output routed through LDS for coalesced h.
// ---------------------------------------------------------------------------
__global__ __launch_bounds__(256) void gemm1_kernel(
    const float* __restrict__ agg1n, const float* __restrict__ x,
    const float* __restrict__ WtA, const float* __restrict__ b1,
    const float* __restrict__ gamma, const float* __restrict__ beta,
    const float* __restrict__ rmean, const float* __restrict__ rvar,
    float* __restrict__ h) {
    __shared__ float As[64][129];
    const int t = threadIdx.x;
    const int wid = __builtin_amdgcn_readfirstlane(t >> 6);
    const int lane = t & 63;
    const int mbase = blockIdx.x * 64;
    const int c0 = wid * 32;
    // opaque zero in a VGPR: compiler can't prove uniformity -> VMEM loads
    const int vz = __builtin_amdgcn_mbcnt_lo(0u, 0u);

    float acc[32];
#pragma unroll
    for (int c = 0; c < 32; ++c) acc[c] = 0.f;

    for (int phase = 0; phase < 2; ++phase) {
        const float* __restrict__ A = phase ? x : agg1n;
        __syncthreads();  // previous phase's readers done before overwrite
#pragma unroll
        for (int i = 0; i < 8; ++i) {
            int e = i * 256 + t;
            int r = e >> 5, k4 = e & 31;
            int rr = mbase + r;
            rr = (rr < N_NODES) ? rr : N_NODES - 1;
            float4 v = ((const float4*)A)[(size_t)rr * 32 + k4];
            *(float4*)&As[r][k4 * 4] = v;
        }
        __syncthreads();
        const float* __restrict__ Wp = WtA + (size_t)(phase << 7) * 128 + c0 + vz;
#pragma unroll 2
        for (int k4 = 0; k4 < 32; ++k4) {
            float4 a4 = *(const float4*)&As[lane][k4 * 4];
            const float4* __restrict__ W0 = (const float4*)(Wp + (size_t)(k4 * 4 + 0) * 128);
            const float4* __restrict__ W1 = (const float4*)(Wp + (size_t)(k4 * 4 + 1) * 128);
            const float4* __restrict__ W2 = (const float4*)(Wp + (size_t)(k4 * 4 + 2) * 128);
            const float4* __restrict__ W3 = (const float4*)(Wp + (size_t)(k4 * 4 + 3) * 128);
#pragma unroll
            for (int q = 0; q < 8; ++q) {
                float4 w0 = W0[q];
                float4 w1 = W1[q];
                float4 w2 = W2[q];
                float4 w3 = W3[q];
                int c = q * 4;
                acc[c + 0] = fmaf(a4.x, w0.x, acc[c + 0]);
                acc[c + 1] = fmaf(a4.x, w0.y, acc[c + 1]);
                acc[c + 2] = fmaf(a4.x, w0.z, acc[c + 2]);
                acc[c + 3] = fmaf(a4.x, w0.w, acc[c + 3]);
                acc[c + 0] = fmaf(a4.y, w1.x, acc[c + 0]);
                acc[c + 1] = fmaf(a4.y, w1.y, acc[c + 1]);
                acc[c + 2] = fmaf(a4.y, w1.z, acc[c + 2]);
                acc[c + 3] = fmaf(a4.y, w1.w, acc[c + 3]);
                acc[c + 0] = fmaf(a4.z, w2.x, acc[c + 0]);
                acc[c + 1] = fmaf(a4.z, w2.y, acc[c + 1]);
                acc[c + 2] = fmaf(a4.z, w2.z, acc[c + 2]);
                acc[c + 3] = fmaf(a4.z, w2.w, acc[c + 3]);
                acc[c + 0] = fmaf(a4.w, w3.x, acc[c + 0]);
                acc[c + 1] = fmaf(a4.w, w3.y, acc[c + 1]);
                acc[c + 2] = fmaf(a4.w, w3.z, acc[c + 2]);
                acc[c + 3] = fmaf(a4.w, w3.w, acc[c + 3]);
            }
        }
    }

    // epilogue: bias + ReLU + BN, via LDS for coalesced stores
    __syncthreads();
#pragma unroll
    for (int q = 0; q < 8; ++q) {
        float rs[4];
#pragma unroll
        for (int u = 0; u < 4; ++u) {
            int c = q * 4 + u;
            float sc = gamma[c0 + c] * rsqrtf(rvar[c0 + c] + BN_EPS);
            float sh = fmaf(-rmean[c0 + c], sc, beta[c0 + c]);
            float pre = acc[c] + b1[c0 + c];
            rs[u] = fmaf(fmaxf(pre, 0.f), sc, sh);
        }
        float4 r = {rs[0], rs[1], rs[2], rs[3]};
        *(float4*)&As[lane][c0 + q * 4] = r;
    }
    __syncthreads();
#pragma unroll
    for (int i = 0; i < 8; ++i) {
        int e = i * 256 + t;
        int r = e >> 5, k4 = e & 31;
        if (mbase + r < N_NODES) {
            float4 v = *(const float4*)&As[r][k4 * 4];
            ((float4*)h)[(size_t)(mbase + r) * 32 + k4] = v;
        }
    }
}

// ---------------------------------------------------------------------------
// GEMM2: [z2 | p2] = h @ WtB. 64 rows x 80 cols, 4 waves x 20 cols (acc[20]),
// h staged once in LDS, weights via vmcnt broadcast loads, outputs copied
// out coalesced via LDS. z2 stride 48 (pad garbage, discarded), p2 stride 40.
// ---------------------------------------------------------------------------
__global__ __launch_bounds__(256) void gemm2_kernel(const float* __restrict__ h,
                                                    const float* __restrict__ WtB,
                                                    float* __restrict__ z2,
                                                    float* __restrict__ p2) {
    __shared__ float As[64][129];
    const int t = threadIdx.x;
    const int wid = __builtin_amdgcn_readfirstlane(t >> 6);
    const int lane = t & 63;
    const int mbase = blockIdx.x * 64;
    const int c0 = wid * 20;
    const int vz = __builtin_amdgcn_mbcnt_lo(0u, 0u);

    float acc[20];
#pragma unroll
    for (int c = 0; c < 20; ++c) acc[c] = 0.f;

#pragma unroll
    for (int i = 0; i < 8; ++i) {
        int e = i * 256 + t;
        int r = e >> 5, k4 = e & 31;
        int rr = mbase + r;
        rr = (rr < N_NODES) ? rr : N_NODES - 1;
        float4 v = ((const float4*)h)[(size_t)rr * 32 + k4];
        *(float4*)&As[r][k4 * 4] = v;
    }
    __syncthreads();
    const float* __restrict__ Wp = WtB + c0 + vz;
#pragma unroll 2
    for (int k4 = 0; k4 < 32; ++k4) {
        float4 a4 = *(const float4*)&As[lane][k4 * 4];
        const float4* __restrict__ W0 = (const float4*)(Wp + (size_t)(k4 * 4 + 0) * 80);
        const float4* __restrict__ W1 = (const float4*)(Wp + (size_t)(k4 * 4 + 1) * 80);
        const float4* __restrict__ W2 = (const float4*)(Wp + (size_t)(k4 * 4 + 2) * 80);
        const float4* __restrict__ W3 = (const float4*)(Wp + (size_t)(k4 * 4 + 3) * 80);
#pragma unroll
        for (int q = 0; q < 5; ++q) {
            float4 w0 = W0[q];
            float4 w1 = W1[q];
            float4 w2 = W2[q];
            float4 w3 = W3[q];
            int c = q * 4;
            acc[c + 0] = fmaf(a4.x, w0.x, acc[c + 0]);
            acc[c + 1] = fmaf(a4.x, w0.y, acc[c + 1]);
            acc[c + 2] = fmaf(a4.x, w0.z, acc[c + 2]);
            acc[c + 3] = fmaf(a4.x, w0.w, acc[c + 3]);
            acc[c + 0] = fmaf(a4.y, w1.x, acc[c + 0]);
            acc[c + 1] = fmaf(a4.y, w1.y, acc[c + 1]);
            acc[c + 2] = fmaf(a4.y, w1.z, acc[c + 2]);
            acc[c + 3] = fmaf(a4.y, w1.w, acc[c + 3]);
            acc[c + 0] = fmaf(a4.z, w2.x, acc[c + 0]);
            acc[c + 1] = fmaf(a4.z, w2.y, acc[c + 1]);
            acc[c + 2] = fmaf(a4.z, w2.z, acc[c + 2]);
            acc[c + 3] = fmaf(a4.z, w2.w, acc[c + 3]);
            acc[c + 0] = fmaf(a4.w, w3.x, acc[c + 0]);
            acc[c + 1] = fmaf(a4.w, w3.y, acc[c + 1]);
            acc[c + 2] = fmaf(a4.w, w3.z, acc[c + 2]);
            acc[c + 3] = fmaf(a4.w, w3.w, acc[c + 3]);
        }
    }

    __syncthreads();
#pragma unroll
    for (int c = 0; c < 20; ++c) As[lane][c0 + c] = acc[c];
    __syncthreads();

    // z2: 64 rows x 12 float4 (cols 0..47; 40..47 garbage, discarded later)
#pragma unroll
    for (int i = 0; i < 3; ++i) {
        int e = i * 256 + t;  // < 768
        int r = e / 12, q = e - r * 12;
        if (mbase + r < N_NODES) {
            float4 v = *(const float4*)&As[r][q * 4];
            *(float4*)(z2 + (size_t)(mbase + r) * 48 + q * 4) = v;
        }
    }
    // p2: 64 rows x 10 float4 (cols 40..79)
    for (int e = t; e < 640; e += 256) {
        int r = e / 10, q = e - r * 10;
        if (mbase + r < N_NODES) {
            float4 v = *(const float4*)&As[r][40 + q * 4];
            *(float4*)(p2 + (size_t)(mbase + r) * 40 + q * 4) = v;
        }
    }
}

// ---------------------------------------------------------------------------
// Gather layer 2 + final: out = mean_s(z2[s]) + p2[r] + b2
// Wave per node, 5 edges/iter: 12 lanes/edge, float4/lane over stride-48 z2
// rows (cols 40..47 read-and-discarded). Shuffle-reduce; lanes 0..9 write.
// ---------------------------------------------------------------------------
__global__ __launch_bounds__(256) void gather2_kernel(const int* __restrict__ csr_src,
                                                      const int* __restrict__ row_ptr,
                                                      const float* __restrict__ z2,
                                                      const float* __restrict__ p2,
                                                      const float* __restrict__ b2,
                                                      float* __restrict__ out) {
    int gid = __builtin_amdgcn_readfirstlane(blockIdx.x * 4 + (threadIdx.x >> 6));
    if (gid >= N_NODES) return;
    int lane = threadIdx.x & 63;
    int sub = lane / 12;          // 0..5 (5 = inactive)
    int li = lane - sub * 12;     // 0..11
    bool active = sub < 5;
    int beg = row_ptr[gid], end = row_ptr[gid + 1];
    int n = end - beg;
    const float4* z4 = (const float4*)z2;
    float4 acc = {0.f, 0.f, 0.f, 0.f};
    int iters = (n + 4) / 5;
    int e = beg + sub;
    for (int it = 0; it < iters; ++it, e += 5) {
        bool v = active && (e < end);
        int ee = v ? e : beg;
        int s = csr_src[ee];
        float4 t = z4[(size_t)s * 12 + li];
        if (v) {
            acc.x += t.x; acc.y += t.y; acc.z += t.z; acc.w += t.w;
        }
    }
    float4 a0 = acc;
#pragma unroll
    for (int k = 1; k <= 4; ++k) {
        float4 t;
        t.x = __shfl(a0.x, lane + 12 * k);
        t.y = __shfl(a0.y, lane + 12 * k);
        t.z = __shfl(a0.z, lane + 12 * k);
        t.w = __shfl(a0.w, lane + 12 * k);
        acc.x += t.x; acc.y += t.y; acc.z += t.z; acc.w += t.w;
    }
    if (sub == 0 && li < 10) {
        float inv = 1.0f / fmaxf((float)n, 1.0f);
        float4 p = ((const float4*)p2)[(size_t)gid * 10 + li];
        float4 bb = ((const float4*)b2)[li];
        float4 r;
        r.x = fmaf(acc.x, inv, p.x + bb.x);
        r.y = fmaf(acc.y, inv, p.y + bb.y);
        r.z = fmaf(acc.z, inv, p.z + bb.z);
        r.w = fmaf(acc.w, inv, p.w + bb.w);
        ((float4*)out)[(size_t)gid * 10 + li] = r;
    }
}

// ---------------------------------------------------------------------------
// Launch. ws layout:
//   int  deg_i[50048], cursor[50048]          (memset 0 together)
//   int  row_ptr[50052], blk_sum[256], blk_off[256], csr_src[800000]
//   f32  WtA[32768], WtB[10240]
//   f32  agg1n[50048*128]   -- z2[50048*48] + p2[50048*40] alias this region
//   f32  h[50048*128]
// ---------------------------------------------------------------------------
extern "C" void kernel_launch(void* const* d_in, const int* in_sizes, int n_in,
                              void* d_out, int out_size, void* d_ws, size_t ws_size,
                              hipStream_t stream) {
    const float* x     = (const float*)d_in[0];
    const int*   ei    = (const int*)d_in[1];
    const float* W1l   = (const float*)d_in[2];
    const float* b1    = (const float*)d_in[3];
    const float* W1r   = (const float*)d_in[4];
    const float* gamma = (const float*)d_in[5];
    const float* beta  = (const float*)d_in[6];
    const float* rmean = (const float*)d_in[7];
    const float* rvar  = (const float*)d_in[8];
    const float* W2l   = (const float*)d_in[9];
    const float* b2    = (const float*)d_in[10];
    const float* W2r   = (const float*)d_in[11];
    float* out = (float*)d_out;

    int* deg_i   = (int*)d_ws;
    int* cursor  = deg_i + 50048;
    int* row_ptr = cursor + 50048;
    int* blk_sum = row_ptr + 50052;
    int* blk_off = blk_sum + 256;
    int* csr_src = blk_off + 256;
    float* WtA   = (float*)(csr_src + 800000);
    float* WtB   = WtA + 32768;
    float* agg1n = WtB + 10240;
    float* z2    = agg1n;                       // alias (agg1n dead after gemm1)
    float* p2    = z2 + (size_t)50048 * 48;
    float* h     = agg1n + (size_t)50048 * 128;

    const int* src = ei;
    const int* dst = ei + N_EDGES;

    hipMemsetAsync(deg_i, 0, (size_t)(50048 + 50048) * sizeof(int), stream);

    deg_kernel<<<(N_EDGES + 255) / 256, 256, 0, stream>>>(dst, deg_i);
    scanA_kernel<<<SCAN_BLOCKS, 256, 0, stream>>>(deg_i, row_ptr, blk_sum);
    scanB_kernel<<<1, 256, 0, stream>>>(blk_sum, blk_off);
    scanC_kernel<<<SCAN_BLOCKS, 256, 0, stream>>>(row_ptr, blk_off);
    fill_kernel<<<(N_EDGES + 255) / 256, 256, 0, stream>>>(src, dst, row_ptr, cursor, csr_src);

    transposeW_kernel<<<168, 256, 0, stream>>>(W1l, W1r, W2l, W2r, WtA, WtB);

    gather1_kernel<<<(N_NODES + 3) / 4, 256, 0, stream>>>(csr_src, row_ptr, x, agg1n);

    gemm1_kernel<<<(N_NODES + 63) / 64, 256, 0, stream>>>(agg1n, x, WtA, b1, gamma,
                                                          beta, rmean, rvar, h);

    gemm2_kernel<<<(N_NODES + 63) / 64, 256, 0, stream>>>(h, WtB, z2, p2);

    gather2_kernel<<<(N_NODES + 3) / 4, 256, 0, stream>>>(csr_src, row_ptr, z2, p2, b2, out);
}

// Round 8
// 327.392 us; speedup vs baseline: 1.7531x; 1.7531x over previous
//
#include <hip/hip_runtime.h>

#define N_NODES 50000
#define N_EDGES 800000
#define N_FEAT 128
#define N_HID 128
#define N_CLS 40
#define BN_EPS 1e-5f

#define SCAN_BLOCKS ((N_NODES + 255) / 256)  // 196

// RNE float->bf16 pack helpers
__device__ __forceinline__ unsigned bfpack(float a, float b) {
    unsigned ua = __float_as_uint(a), ub = __float_as_uint(b);
    ua = (ua + 0x7FFFu + ((ua >> 16) & 1u)) >> 16;
    ub = (ub + 0x7FFFu + ((ub >> 16) & 1u)) >> 16;
    return ua | (ub << 16);
}
__device__ __forceinline__ float bflo(unsigned u) { return __uint_as_float(u << 16); }
__device__ __forceinline__ float bfhi(unsigned u) { return __uint_as_float(u & 0xFFFF0000u); }

// ---------------------------------------------------------------------------
// K1: int degree histogram.
// ---------------------------------------------------------------------------
__global__ __launch_bounds__(256) void deg_kernel(const int* __restrict__ dst,
                                                  int* __restrict__ deg_i) {
    int e = blockIdx.x * 256 + threadIdx.x;
    if (e < N_EDGES) atomicAdd(&deg_i[dst[e]], 1);
}

// ---------------------------------------------------------------------------
// Scan A/B/C: row_ptr = exclusive scan of degrees.
// ---------------------------------------------------------------------------
__global__ __launch_bounds__(256) void scanA_kernel(const int* __restrict__ deg_i,
                                                    int* __restrict__ row_ptr,
                                                    int* __restrict__ blk_sum) {
    __shared__ int tmp[256];
    int t = threadIdx.x;
    int i = blockIdx.x * 256 + t;
    int v = (i < N_NODES) ? deg_i[i] : 0;
    tmp[t] = v;
    __syncthreads();
    for (int off = 1; off < 256; off <<= 1) {
        int a = (t >= off) ? tmp[t - off] : 0;
        __syncthreads();
        if (t >= off) tmp[t] += a;
        __syncthreads();
    }
    if (i < N_NODES) row_ptr[i] = tmp[t] - v;
    if (t == 255) blk_sum[blockIdx.x] = tmp[255];
}

__global__ __launch_bounds__(256) void scanB_kernel(const int* __restrict__ blk_sum,
                                                    int* __restrict__ blk_off) {
    __shared__ int tmp[256];
    int t = threadIdx.x;
    int v = (t < SCAN_BLOCKS) ? blk_sum[t] : 0;
    tmp[t] = v;
    __syncthreads();
    for (int off = 1; off < 256; off <<= 1) {
        int a = (t >= off) ? tmp[t - off] : 0;
        __syncthreads();
        if (t >= off) tmp[t] += a;
        __syncthreads();
    }
    if (t < SCAN_BLOCKS) blk_off[t] = tmp[t] - v;
}

__global__ __launch_bounds__(256) void scanC_kernel(int* __restrict__ row_ptr,
                                                    const int* __restrict__ blk_off) {
    int i = blockIdx.x * 256 + threadIdx.x;
    if (i < N_NODES) row_ptr[i] += blk_off[blockIdx.x];
    if (i == 0) row_ptr[N_NODES] = N_EDGES;
}

// ---------------------------------------------------------------------------
// CSR fill.
// ---------------------------------------------------------------------------
__global__ __launch_bounds__(256) void fill_kernel(const int* __restrict__ src,
                                                   const int* __restrict__ dst,
                                                   const int* __restrict__ row_ptr,
                                                   int* __restrict__ cursor,
                                                   int* __restrict__ csr_src) {
    int e = blockIdx.x * 256 + threadIdx.x;
    if (e >= N_EDGES) return;
    int d = dst[e];
    int pos = atomicAdd(&cursor[d], 1);
    csr_src[row_ptr[d] + pos] = src[e];
}

// ---------------------------------------------------------------------------
// Prep: weight transpose (k-major) + x -> bf16 (RNE), fused.
//   i < 32768          : WtA[k][n] (256x128)
//   i < 43008          : WtB[k][n] (128x80)
//   else j = i-43008   : pack x[j*8..j*8+7] -> x_bf16 (uint4)
// ---------------------------------------------------------------------------
__global__ __launch_bounds__(256) void prep_kernel(
    const float* __restrict__ W1l, const float* __restrict__ W1r,
    const float* __restrict__ W2l, const float* __restrict__ W2r,
    const float* __restrict__ x, float* __restrict__ WtA,
    float* __restrict__ WtB, unsigned* __restrict__ x_bf16) {
    int i = blockIdx.x * 256 + threadIdx.x;
    if (i < 256 * 128) {
        int k = i >> 7, n = i & 127;
        WtA[i] = (k < 128) ? W1l[n * 128 + k] : W1r[n * 128 + (k - 128)];
    } else if (i < 256 * 128 + 128 * 80) {
        int j = i - 256 * 128;
        int k = j / 80, n = j % 80;
        WtB[j] = (n < 40) ? W2l[n * 128 + k] : W2r[(n - 40) * 128 + k];
    } else {
        int j = i - 43008;
        if (j < 800000) {
            const float4* xf = (const float4*)x;
            float4 a = xf[(size_t)j * 2];
            float4 b = xf[(size_t)j * 2 + 1];
            uint4 o;
            o.x = bfpack(a.x, a.y);
            o.y = bfpack(a.z, a.w);
            o.z = bfpack(b.x, b.y);
            o.w = bfpack(b.z, b.w);
            ((uint4*)x_bf16)[j] = o;
        }
    }
}

// ---------------------------------------------------------------------------
// Gather-mean layer 1 (bf16 x): wave per node, 4 edges/iter (16 lanes x
// uint4 = 256B row each), 2x unrolled -> 8 edges in flight. fp32 accumulate,
// xor-shuffle reduce across the 4 subgroups, folds inv_deg. agg1n fp32 out.
// ---------------------------------------------------------------------------
__global__ __launch_bounds__(256) void gather1_kernel(const int* __restrict__ csr_src,
                                                      const int* __restrict__ row_ptr,
                                                      const unsigned* __restrict__ x_bf16,
                                                      float* __restrict__ agg1n) {
    int gid = __builtin_amdgcn_readfirstlane(blockIdx.x * 4 + (threadIdx.x >> 6));
    if (gid >= N_NODES) return;
    int lane = threadIdx.x & 63;
    int sub = lane >> 4;       // 0..3
    int li = lane & 15;        // 0..15
    int beg = row_ptr[gid], end = row_ptr[gid + 1];
    int n = end - beg;
    const uint4* xb = (const uint4*)x_bf16;  // 16 uint4 per 128-feat row
    float acc[8];
#pragma unroll
    for (int j = 0; j < 8; ++j) acc[j] = 0.f;

    int iters = (n + 7) >> 3;  // 8 edges per iter (2 groups of 4)
    int e = beg + sub;
    for (int it = 0; it < iters; ++it, e += 8) {
        bool v0 = (e < end);
        bool v1 = (e + 4 < end);
        int s0 = csr_src[v0 ? e : 0];
        int s1 = csr_src[v1 ? e + 4 : 0];
        uint4 t0 = xb[(size_t)s0 * 16 + li];
        uint4 t1 = xb[(size_t)s1 * 16 + li];
        if (v0) {
            acc[0] += bflo(t0.x); acc[1] += bfhi(t0.x);
            acc[2] += bflo(t0.y); acc[3] += bfhi(t0.y);
            acc[4] += bflo(t0.z); acc[5] += bfhi(t0.z);
            acc[6] += bflo(t0.w); acc[7] += bfhi(t0.w);
        }
        if (v1) {
            acc[0] += bflo(t1.x); acc[1] += bfhi(t1.x);
            acc[2] += bflo(t1.y); acc[3] += bfhi(t1.y);
            acc[4] += bflo(t1.z); acc[5] += bfhi(t1.z);
            acc[6] += bflo(t1.w); acc[7] += bfhi(t1.w);
        }
    }
#pragma unroll
    for (int j = 0; j < 8; ++j) {
        acc[j] += __shfl_xor(acc[j], 16);
        acc[j] += __shfl_xor(acc[j], 32);
    }
    if (sub == 0) {
        float inv = 1.0f / fmaxf((float)n, 1.0f);
        float4 r0 = {acc[0] * inv, acc[1] * inv, acc[2] * inv, acc[3] * inv};
        float4 r1 = {acc[4] * inv, acc[5] * inv, acc[6] * inv, acc[7] * inv};
        float* dst = agg1n + (size_t)gid * 128 + li * 8;
        *(float4*)dst = r0;
        *(float4*)(dst + 4) = r1;
    }
}

// ---------------------------------------------------------------------------
// GEMM1 (R6 structure -- the proven 69.5us version):
// h = BN(ReLU(agg1n @ W1l^T + b1 + x @ W1r^T))
// 64 rows x 128 cols/block; 4 waves x 32-col slice (acc[32]). A staged once
// in LDS [64][129]; weights via wave-uniform s_load. Output through LDS.
// ---------------------------------------------------------------------------
__global__ __launch_bounds__(256) void gemm1_kernel(
    const float* __restrict__ agg1n, const float* __restrict__ x,
    const float* __restrict__ WtA, const float* __restrict__ b1,
    const float* __restrict__ gamma, const float* __restrict__ beta,
    const float* __restrict__ rmean, const float* __restrict__ rvar,
    float* __restrict__ h) {
    __shared__ float As[64][129];
    const int t = threadIdx.x;
    const int wid = __builtin_amdgcn_readfirstlane(t >> 6);
    const int lane = t & 63;
    const int mbase = blockIdx.x * 64;
    const int c0 = wid * 32;

    float acc[32];
#pragma unroll
    for (int c = 0; c < 32; ++c) acc[c] = 0.f;

    for (int phase = 0; phase < 2; ++phase) {
        const float* __restrict__ A = phase ? x : agg1n;
        __syncthreads();
#pragma unroll
        for (int i = 0; i < 8; ++i) {
            int e = i * 256 + t;
            int r = e >> 5, k4 = e & 31;
            int rr = mbase + r;
            rr = (rr < N_NODES) ? rr : N_NODES - 1;
            float4 v = ((const float4*)A)[(size_t)rr * 32 + k4];
            *(float4*)&As[r][k4 * 4] = v;
        }
        __syncthreads();
        const float* __restrict__ Wp = WtA + (size_t)(phase << 7) * 128 + c0;
#pragma unroll 4
        for (int k4 = 0; k4 < 32; ++k4) {
            float4 a4 = *(const float4*)&As[lane][k4 * 4];
#pragma unroll
            for (int j = 0; j < 4; ++j) {
                float av = (j == 0) ? a4.x : (j == 1) ? a4.y : (j == 2) ? a4.z : a4.w;
                const float* __restrict__ Wr = Wp + (size_t)(k4 * 4 + j) * 128;
#pragma unroll
                for (int c = 0; c < 32; ++c) acc[c] = fmaf(av, Wr[c], acc[c]);
            }
        }
    }

    __syncthreads();
#pragma unroll
    for (int q = 0; q < 8; ++q) {
        float rs[4];
#pragma unroll
        for (int u = 0; u < 4; ++u) {
            int c = q * 4 + u;
            float sc = gamma[c0 + c] * rsqrtf(rvar[c0 + c] + BN_EPS);
            float sh = fmaf(-rmean[c0 + c], sc, beta[c0 + c]);
            float pre = acc[c] + b1[c0 + c];
            rs[u] = fmaf(fmaxf(pre, 0.f), sc, sh);
        }
        float4 r = {rs[0], rs[1], rs[2], rs[3]};
        *(float4*)&As[lane][c0 + q * 4] = r;
    }
    __syncthreads();
#pragma unroll
    for (int i = 0; i < 8; ++i) {
        int e = i * 256 + t;
        int r = e >> 5, k4 = e & 31;
        if (mbase + r < N_NODES) {
            float4 v = *(const float4*)&As[r][k4 * 4];
            ((float4*)h)[(size_t)(mbase + r) * 32 + k4] = v;
        }
    }
}

// ---------------------------------------------------------------------------
// GEMM2 (R6 structure): [z2 | p2] = h @ WtB. 64 rows x 80 cols, 4 waves x
// 20 cols (acc[20]), s_load weights, outputs via LDS.
// z2 emitted as PACKED bf16, stride 40 (80 B/row). p2 fp32 stride 40.
// ---------------------------------------------------------------------------
__global__ __launch_bounds__(256) void gemm2_kernel(const float* __restrict__ h,
                                                    const float* __restrict__ WtB,
                                                    unsigned* __restrict__ z2b,
                                                    float* __restrict__ p2) {
    __shared__ float As[64][129];
    const int t = threadIdx.x;
    const int wid = __builtin_amdgcn_readfirstlane(t >> 6);
    const int lane = t & 63;
    const int mbase = blockIdx.x * 64;
    const int c0 = wid * 20;

    float acc[20];
#pragma unroll
    for (int c = 0; c < 20; ++c) acc[c] = 0.f;

#pragma unroll
    for (int i = 0; i < 8; ++i) {
        int e = i * 256 + t;
        int r = e >> 5, k4 = e & 31;
        int rr = mbase + r;
        rr = (rr < N_NODES) ? rr : N_NODES - 1;
        float4 v = ((const float4*)h)[(size_t)rr * 32 + k4];
        *(float4*)&As[r][k4 * 4] = v;
    }
    __syncthreads();
#pragma unroll 4
    for (int k4 = 0; k4 < 32; ++k4) {
        float4 a4 = *(const float4*)&As[lane][k4 * 4];
#pragma unroll
        for (int j = 0; j < 4; ++j) {
            float av = (j == 0) ? a4.x : (j == 1) ? a4.y : (j == 2) ? a4.z : a4.w;
            const float* __restrict__ Wr = WtB + (size_t)(k4 * 4 + j) * 80 + c0;
#pragma unroll
            for (int c = 0; c < 20; ++c) acc[c] = fmaf(av, Wr[c], acc[c]);
        }
    }

    __syncthreads();
#pragma unroll
    for (int c = 0; c < 20; ++c) As[lane][c0 + c] = acc[c];
    __syncthreads();

    // z2 bf16: 64 rows x 10 uint2 (cols 4q..4q+3 per uint2)
    for (int e = t; e < 640; e += 256) {
        int r = e / 10, q = e - r * 10;
        if (mbase + r < N_NODES) {
            float4 v = *(const float4*)&As[r][q * 4];
            uint2 o;
            o.x = bfpack(v.x, v.y);
            o.y = bfpack(v.z, v.w);
            ((uint2*)z2b)[(size_t)(mbase + r) * 10 + q] = o;
        }
    }
    // p2 fp32: 64 rows x 10 float4 (cols 40..79)
    for (int e = t; e < 640; e += 256) {
        int r = e / 10, q = e - r * 10;
        if (mbase + r < N_NODES) {
            float4 v = *(const float4*)&As[r][40 + q * 4];
            *(float4*)(p2 + (size_t)(mbase + r) * 40 + q * 4) = v;
        }
    }
}

// ---------------------------------------------------------------------------
// Gather layer 2 + final (bf16 z2): out = mean_s(z2[s]) + p2[r] + b2
// Wave per node, 6 edges/iter (10 lanes x uint2 = 80B row), 2x unrolled ->
// 12 in flight. Gather-sum the 6 subgroups via shuffles; lanes 0..9 write.
// ---------------------------------------------------------------------------
__global__ __launch_bounds__(256) void gather2_kernel(const int* __restrict__ csr_src,
                                                      const int* __restrict__ row_ptr,
                                                      const unsigned* __restrict__ z2b,
                                                      const float* __restrict__ p2,
                                                      const float* __restrict__ b2,
                                                      float* __restrict__ out) {
    int gid = __builtin_amdgcn_readfirstlane(blockIdx.x * 4 + (threadIdx.x >> 6));
    if (gid >= N_NODES) return;
    int lane = threadIdx.x & 63;
    int sub = lane / 10;          // 0..6 (6 = inactive)
    int li = lane - sub * 10;     // 0..9
    bool active = sub < 6;
    int beg = row_ptr[gid], end = row_ptr[gid + 1];
    int n = end - beg;
    const uint2* z2 = (const uint2*)z2b;  // 10 uint2 per row
    float4 acc = {0.f, 0.f, 0.f, 0.f};
    int iters = (n + 11) / 12;  // 12 edges per iter (2 groups of 6)
    int e = beg + sub;
    for (int it = 0; it < iters; ++it, e += 12) {
        bool v0 = active && (e < end);
        bool v1 = active && (e + 6 < end);
        int s0 = csr_src[v0 ? e : 0];
        int s1 = csr_src[v1 ? e + 6 : 0];
        uint2 t0 = z2[(size_t)s0 * 10 + li];
        uint2 t1 = z2[(size_t)s1 * 10 + li];
        if (v0) {
            acc.x += bflo(t0.x); acc.y += bfhi(t0.x);
            acc.z += bflo(t0.y); acc.w += bfhi(t0.y);
        }
        if (v1) {
            acc.x += bflo(t1.x); acc.y += bfhi(t1.x);
            acc.z += bflo(t1.y); acc.w += bfhi(t1.y);
        }
    }
    float4 a0 = acc;
#pragma unroll
    for (int k = 1; k <= 5; ++k) {
        float4 t;
        t.x = __shfl(a0.x, lane + 10 * k);
        t.y = __shfl(a0.y, lane + 10 * k);
        t.z = __shfl(a0.z, lane + 10 * k);
        t.w = __shfl(a0.w, lane + 10 * k);
        acc.x += t.x; acc.y += t.y; acc.z += t.z; acc.w += t.w;
    }
    if (sub == 0) {
        float inv = 1.0f / fmaxf((float)n, 1.0f);
        float4 p = ((const float4*)p2)[(size_t)gid * 10 + li];
        float4 bb = ((const float4*)b2)[li];
        float4 r;
        r.x = fmaf(acc.x, inv, p.x + bb.x);
        r.y = fmaf(acc.y, inv, p.y + bb.y);
        r.z = fmaf(acc.z, inv, p.z + bb.z);
        r.w = fmaf(acc.w, inv, p.w + bb.w);
        ((float4*)out)[(size_t)gid * 10 + li] = r;
    }
}

// ---------------------------------------------------------------------------
// Launch. ws layout:
//   int  deg_i[50048], cursor[50048]          (memset 0 together)
//   int  row_ptr[50052], blk_sum[256], blk_off[256], csr_src[800000]
//   f32  WtA[32768], WtB[10240]
//   u32  x_bf16[3200000]                      (6.4M bf16)
//   f32  agg1n[50048*128]  -- z2b[50048*20 u32] + p2[50048*40 f32] alias it
//   f32  h[50048*128]
// Total ~68 MB.
// ---------------------------------------------------------------------------
extern "C" void kernel_launch(void* const* d_in, const int* in_sizes, int n_in,
                              void* d_out, int out_size, void* d_ws, size_t ws_size,
                              hipStream_t stream) {
    const float* x     = (const float*)d_in[0];
    const int*   ei    = (const int*)d_in[1];
    const float* W1l   = (const float*)d_in[2];
    const float* b1    = (const float*)d_in[3];
    const float* W1r   = (const float*)d_in[4];
    const float* gamma = (const float*)d_in[5];
    const float* beta  = (const float*)d_in[6];
    const float* rmean = (const float*)d_in[7];
    const float* rvar  = (const float*)d_in[8];
    const float* W2l   = (const float*)d_in[9];
    const float* b2    = (const float*)d_in[10];
    const float* W2r   = (const float*)d_in[11];
    float* out = (float*)d_out;

    int* deg_i       = (int*)d_ws;
    int* cursor      = deg_i + 50048;
    int* row_ptr     = cursor + 50048;
    int* blk_sum     = row_ptr + 50052;
    int* blk_off     = blk_sum + 256;
    int* csr_src     = blk_off + 256;
    float* WtA       = (float*)(csr_src + 800000);
    float* WtB       = WtA + 32768;
    unsigned* x_bf16 = (unsigned*)(WtB + 10240);
    float* agg1n     = (float*)(x_bf16 + 3200000);
    unsigned* z2b    = (unsigned*)agg1n;            // alias (agg1n dead after gemm1)
    float* p2        = agg1n + 50048 * 20;          // after z2b's 50048*20 u32
    float* h         = agg1n + (size_t)50048 * 128;

    const int* src = ei;
    const int* dst = ei + N_EDGES;

    hipMemsetAsync(deg_i, 0, (size_t)(50048 + 50048) * sizeof(int), stream);

    deg_kernel<<<(N_EDGES + 255) / 256, 256, 0, stream>>>(dst, deg_i);
    scanA_kernel<<<SCAN_BLOCKS, 256, 0, stream>>>(deg_i, row_ptr, blk_sum);
    scanB_kernel<<<1, 256, 0, stream>>>(blk_sum, blk_off);
    scanC_kernel<<<SCAN_BLOCKS, 256, 0, stream>>>(row_ptr, blk_off);
    fill_kernel<<<(N_EDGES + 255) / 256, 256, 0, stream>>>(src, dst, row_ptr, cursor, csr_src);

    prep_kernel<<<(43008 + 800000 + 255) / 256, 256, 0, stream>>>(W1l, W1r, W2l, W2r,
                                                                  x, WtA, WtB, x_bf16);

    gather1_kernel<<<(N_NODES + 3) / 4, 256, 0, stream>>>(csr_src, row_ptr, x_bf16, agg1n);

    gemm1_kernel<<<(N_NODES + 63) / 64, 256, 0, stream>>>(agg1n, x, WtA, b1, gamma,
                                                          beta, rmean, rvar, h);

    gemm2_kernel<<<(N_NODES + 63) / 64, 256, 0, stream>>>(h, WtB, z2b, p2);

    gather2_kernel<<<(N_NODES + 3) / 4, 256, 0, stream>>>(csr_src, row_ptr, z2b, p2, b2, out);
}

// Round 9
// 319.675 us; speedup vs baseline: 1.7954x; 1.0241x over previous
//
#include <hip/hip_runtime.h>

#define N_NODES 50000
#define N_EDGES 800000
#define N_FEAT 128
#define N_HID 128
#define N_CLS 40
#define BN_EPS 1e-5f

#define SCAN_BLOCKS ((N_NODES + 255) / 256)  // 196

// RNE float->bf16 pack helpers
__device__ __forceinline__ unsigned bfpack(float a, float b) {
    unsigned ua = __float_as_uint(a), ub = __float_as_uint(b);
    ua = (ua + 0x7FFFu + ((ua >> 16) & 1u)) >> 16;
    ub = (ub + 0x7FFFu + ((ub >> 16) & 1u)) >> 16;
    return ua | (ub << 16);
}
__device__ __forceinline__ float bflo(unsigned u) { return __uint_as_float(u << 16); }
__device__ __forceinline__ float bfhi(unsigned u) { return __uint_as_float(u & 0xFFFF0000u); }

// ---------------------------------------------------------------------------
// K1: int degree histogram.
// ---------------------------------------------------------------------------
__global__ __launch_bounds__(256) void deg_kernel(const int* __restrict__ dst,
                                                  int* __restrict__ deg_i) {
    int e = blockIdx.x * 256 + threadIdx.x;
    if (e < N_EDGES) atomicAdd(&deg_i[dst[e]], 1);
}

// ---------------------------------------------------------------------------
// Scan A/B/C: row_ptr = exclusive scan of degrees.
// ---------------------------------------------------------------------------
__global__ __launch_bounds__(256) void scanA_kernel(const int* __restrict__ deg_i,
                                                    int* __restrict__ row_ptr,
                                                    int* __restrict__ blk_sum) {
    __shared__ int tmp[256];
    int t = threadIdx.x;
    int i = blockIdx.x * 256 + t;
    int v = (i < N_NODES) ? deg_i[i] : 0;
    tmp[t] = v;
    __syncthreads();
    for (int off = 1; off < 256; off <<= 1) {
        int a = (t >= off) ? tmp[t - off] : 0;
        __syncthreads();
        if (t >= off) tmp[t] += a;
        __syncthreads();
    }
    if (i < N_NODES) row_ptr[i] = tmp[t] - v;
    if (t == 255) blk_sum[blockIdx.x] = tmp[255];
}

__global__ __launch_bounds__(256) void scanB_kernel(const int* __restrict__ blk_sum,
                                                    int* __restrict__ blk_off) {
    __shared__ int tmp[256];
    int t = threadIdx.x;
    int v = (t < SCAN_BLOCKS) ? blk_sum[t] : 0;
    tmp[t] = v;
    __syncthreads();
    for (int off = 1; off < 256; off <<= 1) {
        int a = (t >= off) ? tmp[t - off] : 0;
        __syncthreads();
        if (t >= off) tmp[t] += a;
        __syncthreads();
    }
    if (t < SCAN_BLOCKS) blk_off[t] = tmp[t] - v;
}

__global__ __launch_bounds__(256) void scanC_kernel(int* __restrict__ row_ptr,
                                                    const int* __restrict__ blk_off) {
    int i = blockIdx.x * 256 + threadIdx.x;
    if (i < N_NODES) row_ptr[i] += blk_off[blockIdx.x];
    if (i == 0) row_ptr[N_NODES] = N_EDGES;
}

// ---------------------------------------------------------------------------
// CSR fill.
// ---------------------------------------------------------------------------
__global__ __launch_bounds__(256) void fill_kernel(const int* __restrict__ src,
                                                   const int* __restrict__ dst,
                                                   const int* __restrict__ row_ptr,
                                                   int* __restrict__ cursor,
                                                   int* __restrict__ csr_src) {
    int e = blockIdx.x * 256 + threadIdx.x;
    if (e >= N_EDGES) return;
    int d = dst[e];
    int pos = atomicAdd(&cursor[d], 1);
    csr_src[row_ptr[d] + pos] = src[e];
}

// ---------------------------------------------------------------------------
// Prep: weight transpose (k-major) + x -> bf16 (RNE), fused.
// ---------------------------------------------------------------------------
__global__ __launch_bounds__(256) void prep_kernel(
    const float* __restrict__ W1l, const float* __restrict__ W1r,
    const float* __restrict__ W2l, const float* __restrict__ W2r,
    const float* __restrict__ x, float* __restrict__ WtA,
    float* __restrict__ WtB, unsigned* __restrict__ x_bf16) {
    int i = blockIdx.x * 256 + threadIdx.x;
    if (i < 256 * 128) {
        int k = i >> 7, n = i & 127;
        WtA[i] = (k < 128) ? W1l[n * 128 + k] : W1r[n * 128 + (k - 128)];
    } else if (i < 256 * 128 + 128 * 80) {
        int j = i - 256 * 128;
        int k = j / 80, n = j % 80;
        WtB[j] = (n < 40) ? W2l[n * 128 + k] : W2r[(n - 40) * 128 + k];
    } else {
        int j = i - 43008;
        if (j < 800000) {
            const float4* xf = (const float4*)x;
            float4 a = xf[(size_t)j * 2];
            float4 b = xf[(size_t)j * 2 + 1];
            uint4 o;
            o.x = bfpack(a.x, a.y);
            o.y = bfpack(a.z, a.w);
            o.z = bfpack(b.x, b.y);
            o.w = bfpack(b.z, b.w);
            ((uint4*)x_bf16)[j] = o;
        }
    }
}

// ---------------------------------------------------------------------------
// Gather-mean layer 1 (bf16 x): SUBGROUP-PER-NODE, shuffle-free.
// 16 lanes own a node (16 x uint4 = 256B row/edge); 4 edges in flight
// (4 independent loads/lane); fp32 accumulate; lanes write their 8 output
// floats directly. Block = 16 nodes. No cross-lane ops at all.
// ---------------------------------------------------------------------------
__global__ __launch_bounds__(256) void gather1_kernel(const int* __restrict__ csr_src,
                                                      const int* __restrict__ row_ptr,
                                                      const unsigned* __restrict__ x_bf16,
                                                      float* __restrict__ agg1n) {
    int sg = threadIdx.x >> 4;     // 0..15: subgroup = node
    int li = threadIdx.x & 15;     // lane within subgroup
    int gid = blockIdx.x * 16 + sg;
    if (gid >= N_NODES) return;
    int beg = row_ptr[gid], end = row_ptr[gid + 1];
    int n = end - beg;
    const uint4* xb = (const uint4*)x_bf16;  // 16 uint4 per 128-feat row
    float acc[8];
#pragma unroll
    for (int j = 0; j < 8; ++j) acc[j] = 0.f;

    int e = beg;
    for (; e + 3 < end; e += 4) {
        int s0 = csr_src[e], s1 = csr_src[e + 1];
        int s2 = csr_src[e + 2], s3 = csr_src[e + 3];
        uint4 t0 = xb[(size_t)s0 * 16 + li];
        uint4 t1 = xb[(size_t)s1 * 16 + li];
        uint4 t2 = xb[(size_t)s2 * 16 + li];
        uint4 t3 = xb[(size_t)s3 * 16 + li];
        acc[0] += bflo(t0.x) + bflo(t1.x) + bflo(t2.x) + bflo(t3.x);
        acc[1] += bfhi(t0.x) + bfhi(t1.x) + bfhi(t2.x) + bfhi(t3.x);
        acc[2] += bflo(t0.y) + bflo(t1.y) + bflo(t2.y) + bflo(t3.y);
        acc[3] += bfhi(t0.y) + bfhi(t1.y) + bfhi(t2.y) + bfhi(t3.y);
        acc[4] += bflo(t0.z) + bflo(t1.z) + bflo(t2.z) + bflo(t3.z);
        acc[5] += bfhi(t0.z) + bfhi(t1.z) + bfhi(t2.z) + bfhi(t3.z);
        acc[6] += bflo(t0.w) + bflo(t1.w) + bflo(t2.w) + bflo(t3.w);
        acc[7] += bfhi(t0.w) + bfhi(t1.w) + bfhi(t2.w) + bfhi(t3.w);
    }
    for (; e < end; ++e) {
        int s = csr_src[e];
        uint4 t0 = xb[(size_t)s * 16 + li];
        acc[0] += bflo(t0.x); acc[1] += bfhi(t0.x);
        acc[2] += bflo(t0.y); acc[3] += bfhi(t0.y);
        acc[4] += bflo(t0.z); acc[5] += bfhi(t0.z);
        acc[6] += bflo(t0.w); acc[7] += bfhi(t0.w);
    }
    float inv = 1.0f / fmaxf((float)n, 1.0f);
    float4 r0 = {acc[0] * inv, acc[1] * inv, acc[2] * inv, acc[3] * inv};
    float4 r1 = {acc[4] * inv, acc[5] * inv, acc[6] * inv, acc[7] * inv};
    float* dst = agg1n + (size_t)gid * 128 + li * 8;
    *(float4*)dst = r0;
    *(float4*)(dst + 4) = r1;
}

// ---------------------------------------------------------------------------
// GEMM1 (R6 structure -- proven): h = BN(ReLU(agg1n@W1l^T + b1 + x@W1r^T))
// 64 rows x 128 cols/block; 4 waves x 32-col slice (acc[32]). A staged once
// in LDS [64][129]; weights via wave-uniform s_load. Output through LDS.
// ---------------------------------------------------------------------------
__global__ __launch_bounds__(256) void gemm1_kernel(
    const float* __restrict__ agg1n, const float* __restrict__ x,
    const float* __restrict__ WtA, const float* __restrict__ b1,
    const float* __restrict__ gamma, const float* __restrict__ beta,
    const float* __restrict__ rmean, const float* __restrict__ rvar,
    float* __restrict__ h) {
    __shared__ float As[64][129];
    const int t = threadIdx.x;
    const int wid = __builtin_amdgcn_readfirstlane(t >> 6);
    const int lane = t & 63;
    const int mbase = blockIdx.x * 64;
    const int c0 = wid * 32;

    float acc[32];
#pragma unroll
    for (int c = 0; c < 32; ++c) acc[c] = 0.f;

    for (int phase = 0; phase < 2; ++phase) {
        const float* __restrict__ A = phase ? x : agg1n;
        __syncthreads();
#pragma unroll
        for (int i = 0; i < 8; ++i) {
            int e = i * 256 + t;
            int r = e >> 5, k4 = e & 31;
            int rr = mbase + r;
            rr = (rr < N_NODES) ? rr : N_NODES - 1;
            float4 v = ((const float4*)A)[(size_t)rr * 32 + k4];
            *(float4*)&As[r][k4 * 4] = v;
        }
        __syncthreads();
        const float* __restrict__ Wp = WtA + (size_t)(phase << 7) * 128 + c0;
#pragma unroll 4
        for (int k4 = 0; k4 < 32; ++k4) {
            float4 a4 = *(const float4*)&As[lane][k4 * 4];
#pragma unroll
            for (int j = 0; j < 4; ++j) {
                float av = (j == 0) ? a4.x : (j == 1) ? a4.y : (j == 2) ? a4.z : a4.w;
                const float* __restrict__ Wr = Wp + (size_t)(k4 * 4 + j) * 128;
#pragma unroll
                for (int c = 0; c < 32; ++c) acc[c] = fmaf(av, Wr[c], acc[c]);
            }
        }
    }

    __syncthreads();
#pragma unroll
    for (int q = 0; q < 8; ++q) {
        float rs[4];
#pragma unroll
        for (int u = 0; u < 4; ++u) {
            int c = q * 4 + u;
            float sc = gamma[c0 + c] * rsqrtf(rvar[c0 + c] + BN_EPS);
            float sh = fmaf(-rmean[c0 + c], sc, beta[c0 + c]);
            float pre = acc[c] + b1[c0 + c];
            rs[u] = fmaf(fmaxf(pre, 0.f), sc, sh);
        }
        float4 r = {rs[0], rs[1], rs[2], rs[3]};
        *(float4*)&As[lane][c0 + q * 4] = r;
    }
    __syncthreads();
#pragma unroll
    for (int i = 0; i < 8; ++i) {
        int e = i * 256 + t;
        int r = e >> 5, k4 = e & 31;
        if (mbase + r < N_NODES) {
            float4 v = *(const float4*)&As[r][k4 * 4];
            ((float4*)h)[(size_t)(mbase + r) * 32 + k4] = v;
        }
    }
}

// ---------------------------------------------------------------------------
// GEMM2 (R6 structure): [z2 | p2] = h @ WtB. 64 rows x 80 cols, 4 waves x
// 20 cols (acc[20]), s_load weights, outputs via LDS.
// z2 emitted as PACKED bf16, stride 40 (80 B/row). p2 fp32 stride 40.
// ---------------------------------------------------------------------------
__global__ __launch_bounds__(256) void gemm2_kernel(const float* __restrict__ h,
                                                    const float* __restrict__ WtB,
                                                    unsigned* __restrict__ z2b,
                                                    float* __restrict__ p2) {
    __shared__ float As[64][129];
    const int t = threadIdx.x;
    const int wid = __builtin_amdgcn_readfirstlane(t >> 6);
    const int lane = t & 63;
    const int mbase = blockIdx.x * 64;
    const int c0 = wid * 20;

    float acc[20];
#pragma unroll
    for (int c = 0; c < 20; ++c) acc[c] = 0.f;

#pragma unroll
    for (int i = 0; i < 8; ++i) {
        int e = i * 256 + t;
        int r = e >> 5, k4 = e & 31;
        int rr = mbase + r;
        rr = (rr < N_NODES) ? rr : N_NODES - 1;
        float4 v = ((const float4*)h)[(size_t)rr * 32 + k4];
        *(float4*)&As[r][k4 * 4] = v;
    }
    __syncthreads();
#pragma unroll 4
    for (int k4 = 0; k4 < 32; ++k4) {
        float4 a4 = *(const float4*)&As[lane][k4 * 4];
#pragma unroll
        for (int j = 0; j < 4; ++j) {
            float av = (j == 0) ? a4.x : (j == 1) ? a4.y : (j == 2) ? a4.z : a4.w;
            const float* __restrict__ Wr = WtB + (size_t)(k4 * 4 + j) * 80 + c0;
#pragma unroll
            for (int c = 0; c < 20; ++c) acc[c] = fmaf(av, Wr[c], acc[c]);
        }
    }

    __syncthreads();
#pragma unroll
    for (int c = 0; c < 20; ++c) As[lane][c0 + c] = acc[c];
    __syncthreads();

    // z2 bf16: 64 rows x 10 uint2 (cols 4q..4q+3 per uint2)
    for (int e = t; e < 640; e += 256) {
        int r = e / 10, q = e - r * 10;
        if (mbase + r < N_NODES) {
            float4 v = *(const float4*)&As[r][q * 4];
            uint2 o;
            o.x = bfpack(v.x, v.y);
            o.y = bfpack(v.z, v.w);
            ((uint2*)z2b)[(size_t)(mbase + r) * 10 + q] = o;
        }
    }
    // p2 fp32: 64 rows x 10 float4 (cols 40..79)
    for (int e = t; e < 640; e += 256) {
        int r = e / 10, q = e - r * 10;
        if (mbase + r < N_NODES) {
            float4 v = *(const float4*)&As[r][40 + q * 4];
            *(float4*)(p2 + (size_t)(mbase + r) * 40 + q * 4) = v;
        }
    }
}

// ---------------------------------------------------------------------------
// Gather layer 2 + final (bf16 z2): SUBGROUP-PER-NODE, shuffle-free.
// 10 lanes own a node (10 x uint2 = 80B row/edge); 25 subgroups per block
// (6 idle lanes); 4 edges in flight. Epilogue fuses mean + p2 + b2.
// ---------------------------------------------------------------------------
__global__ __launch_bounds__(256) void gather2_kernel(const int* __restrict__ csr_src,
                                                      const int* __restrict__ row_ptr,
                                                      const unsigned* __restrict__ z2b,
                                                      const float* __restrict__ p2,
                                                      const float* __restrict__ b2,
                                                      float* __restrict__ out) {
    int t = threadIdx.x;
    int sub = t / 10;             // 0..25 (25 = idle)
    int li = t - sub * 10;        // 0..9
    if (sub >= 25) return;
    int gid = blockIdx.x * 25 + sub;
    if (gid >= N_NODES) return;
    int beg = row_ptr[gid], end = row_ptr[gid + 1];
    int n = end - beg;
    const uint2* z2 = (const uint2*)z2b;  // 10 uint2 per row
    float4 acc = {0.f, 0.f, 0.f, 0.f};
    int e = beg;
    for (; e + 3 < end; e += 4) {
        int s0 = csr_src[e], s1 = csr_src[e + 1];
        int s2 = csr_src[e + 2], s3 = csr_src[e + 3];
        uint2 t0 = z2[(size_t)s0 * 10 + li];
        uint2 t1 = z2[(size_t)s1 * 10 + li];
        uint2 t2 = z2[(size_t)s2 * 10 + li];
        uint2 t3 = z2[(size_t)s3 * 10 + li];
        acc.x += bflo(t0.x) + bflo(t1.x) + bflo(t2.x) + bflo(t3.x);
        acc.y += bfhi(t0.x) + bfhi(t1.x) + bfhi(t2.x) + bfhi(t3.x);
        acc.z += bflo(t0.y) + bflo(t1.y) + bflo(t2.y) + bflo(t3.y);
        acc.w += bfhi(t0.y) + bfhi(t1.y) + bfhi(t2.y) + bfhi(t3.y);
    }
    for (; e < end; ++e) {
        int s = csr_src[e];
        uint2 t0 = z2[(size_t)s * 10 + li];
        acc.x += bflo(t0.x); acc.y += bfhi(t0.x);
        acc.z += bflo(t0.y); acc.w += bfhi(t0.y);
    }
    float inv = 1.0f / fmaxf((float)n, 1.0f);
    float4 p = ((const float4*)p2)[(size_t)gid * 10 + li];
    float4 bb = ((const float4*)b2)[li];
    float4 r;
    r.x = fmaf(acc.x, inv, p.x + bb.x);
    r.y = fmaf(acc.y, inv, p.y + bb.y);
    r.z = fmaf(acc.z, inv, p.z + bb.z);
    r.w = fmaf(acc.w, inv, p.w + bb.w);
    ((float4*)out)[(size_t)gid * 10 + li] = r;
}

// ---------------------------------------------------------------------------
// Launch. ws layout:
//   int  deg_i[50048], cursor[50048]          (memset 0 together)
//   int  row_ptr[50052], blk_sum[256], blk_off[256], csr_src[800000]
//   f32  WtA[32768], WtB[10240]
//   u32  x_bf16[3200000]                      (6.4M bf16)
//   f32  agg1n[50048*128]  -- z2b[50048*20 u32] + p2[50048*40 f32] alias it
//   f32  h[50048*128]
// ---------------------------------------------------------------------------
extern "C" void kernel_launch(void* const* d_in, const int* in_sizes, int n_in,
                              void* d_out, int out_size, void* d_ws, size_t ws_size,
                              hipStream_t stream) {
    const float* x     = (const float*)d_in[0];
    const int*   ei    = (const int*)d_in[1];
    const float* W1l   = (const float*)d_in[2];
    const float* b1    = (const float*)d_in[3];
    const float* W1r   = (const float*)d_in[4];
    const float* gamma = (const float*)d_in[5];
    const float* beta  = (const float*)d_in[6];
    const float* rmean = (const float*)d_in[7];
    const float* rvar  = (const float*)d_in[8];
    const float* W2l   = (const float*)d_in[9];
    const float* b2    = (const float*)d_in[10];
    const float* W2r   = (const float*)d_in[11];
    float* out = (float*)d_out;

    int* deg_i       = (int*)d_ws;
    int* cursor      = deg_i + 50048;
    int* row_ptr     = cursor + 50048;
    int* blk_sum     = row_ptr + 50052;
    int* blk_off     = blk_sum + 256;
    int* csr_src     = blk_off + 256;
    float* WtA       = (float*)(csr_src + 800000);
    float* WtB       = WtA + 32768;
    unsigned* x_bf16 = (unsigned*)(WtB + 10240);
    float* agg1n     = (float*)(x_bf16 + 3200000);
    unsigned* z2b    = (unsigned*)agg1n;            // alias (agg1n dead after gemm1)
    float* p2        = agg1n + 50048 * 20;          // after z2b's 50048*20 u32
    float* h         = agg1n + (size_t)50048 * 128;

    const int* src = ei;
    const int* dst = ei + N_EDGES;

    hipMemsetAsync(deg_i, 0, (size_t)(50048 + 50048) * sizeof(int), stream);

    deg_kernel<<<(N_EDGES + 255) / 256, 256, 0, stream>>>(dst, deg_i);
    scanA_kernel<<<SCAN_BLOCKS, 256, 0, stream>>>(deg_i, row_ptr, blk_sum);
    scanB_kernel<<<1, 256, 0, stream>>>(blk_sum, blk_off);
    scanC_kernel<<<SCAN_BLOCKS, 256, 0, stream>>>(row_ptr, blk_off);
    fill_kernel<<<(N_EDGES + 255) / 256, 256, 0, stream>>>(src, dst, row_ptr, cursor, csr_src);

    prep_kernel<<<(43008 + 800000 + 255) / 256, 256, 0, stream>>>(W1l, W1r, W2l, W2r,
                                                                  x, WtA, WtB, x_bf16);

    gather1_kernel<<<(N_NODES + 15) / 16, 256, 0, stream>>>(csr_src, row_ptr, x_bf16, agg1n);

    gemm1_kernel<<<(N_NODES + 63) / 64, 256, 0, stream>>>(agg1n, x, WtA, b1, gamma,
                                                          beta, rmean, rvar, h);

    gemm2_kernel<<<(N_NODES + 63) / 64, 256, 0, stream>>>(h, WtB, z2b, p2);

    gather2_kernel<<<(N_NODES + 24) / 25, 256, 0, stream>>>(csr_src, row_ptr, z2b, p2, b2, out);
}

// Round 10
// 276.808 us; speedup vs baseline: 2.0734x; 1.1549x over previous
//
#include <hip/hip_runtime.h>

#define N_NODES 50000
#define N_EDGES 800000
#define N_FEAT 128
#define N_HID 128
#define N_CLS 40
#define BN_EPS 1e-5f

#define SCAN_BLOCKS ((N_NODES + 255) / 256)  // 196

typedef short bf16x8 __attribute__((ext_vector_type(8)));
typedef float f32x4 __attribute__((ext_vector_type(4)));

// RNE float->bf16 pack helpers
__device__ __forceinline__ unsigned bfpack(float a, float b) {
    unsigned ua = __float_as_uint(a), ub = __float_as_uint(b);
    ua = (ua + 0x7FFFu + ((ua >> 16) & 1u)) >> 16;
    ub = (ub + 0x7FFFu + ((ub >> 16) & 1u)) >> 16;
    return ua | (ub << 16);
}
__device__ __forceinline__ float bflo(unsigned u) { return __uint_as_float(u << 16); }
__device__ __forceinline__ float bfhi(unsigned u) { return __uint_as_float(u & 0xFFFF0000u); }

// ---------------------------------------------------------------------------
// K1: int degree histogram.
// ---------------------------------------------------------------------------
__global__ __launch_bounds__(256) void deg_kernel(const int* __restrict__ dst,
                                                  int* __restrict__ deg_i) {
    int e = blockIdx.x * 256 + threadIdx.x;
    if (e < N_EDGES) atomicAdd(&deg_i[dst[e]], 1);
}

// ---------------------------------------------------------------------------
// Scan A/B/C: row_ptr = exclusive scan of degrees.
// ---------------------------------------------------------------------------
__global__ __launch_bounds__(256) void scanA_kernel(const int* __restrict__ deg_i,
                                                    int* __restrict__ row_ptr,
                                                    int* __restrict__ blk_sum) {
    __shared__ int tmp[256];
    int t = threadIdx.x;
    int i = blockIdx.x * 256 + t;
    int v = (i < N_NODES) ? deg_i[i] : 0;
    tmp[t] = v;
    __syncthreads();
    for (int off = 1; off < 256; off <<= 1) {
        int a = (t >= off) ? tmp[t - off] : 0;
        __syncthreads();
        if (t >= off) tmp[t] += a;
        __syncthreads();
    }
    if (i < N_NODES) row_ptr[i] = tmp[t] - v;
    if (t == 255) blk_sum[blockIdx.x] = tmp[255];
}

__global__ __launch_bounds__(256) void scanB_kernel(const int* __restrict__ blk_sum,
                                                    int* __restrict__ blk_off) {
    __shared__ int tmp[256];
    int t = threadIdx.x;
    int v = (t < SCAN_BLOCKS) ? blk_sum[t] : 0;
    tmp[t] = v;
    __syncthreads();
    for (int off = 1; off < 256; off <<= 1) {
        int a = (t >= off) ? tmp[t - off] : 0;
        __syncthreads();
        if (t >= off) tmp[t] += a;
        __syncthreads();
    }
    if (t < SCAN_BLOCKS) blk_off[t] = tmp[t] - v;
}

__global__ __launch_bounds__(256) void scanC_kernel(int* __restrict__ row_ptr,
                                                    const int* __restrict__ blk_off) {
    int i = blockIdx.x * 256 + threadIdx.x;
    if (i < N_NODES) row_ptr[i] += blk_off[blockIdx.x];
    if (i == 0) row_ptr[N_NODES] = N_EDGES;
}

// ---------------------------------------------------------------------------
// CSR fill.
// ---------------------------------------------------------------------------
__global__ __launch_bounds__(256) void fill_kernel(const int* __restrict__ src,
                                                   const int* __restrict__ dst,
                                                   const int* __restrict__ row_ptr,
                                                   int* __restrict__ cursor,
                                                   int* __restrict__ csr_src) {
    int e = blockIdx.x * 256 + threadIdx.x;
    if (e >= N_EDGES) return;
    int d = dst[e];
    int pos = atomicAdd(&cursor[d], 1);
    csr_src[row_ptr[d] + pos] = src[e];
}

// ---------------------------------------------------------------------------
// Prep:
//   i < 16384           : WfA fragment-major bf16 weights for MFMA gemm1.
//     uint i: frag f=i>>8 (f = phase*32 + kc*8 + nt), r=i&255, lane=r>>2,
//     u=r&3. k0 = phase*128 + kc*32 + (lane>>4)*8 + u*2; n = nt*16+(lane&15).
//     WfA[i] = pack(w(k0,n), w(k0+1,n)), w = k<128 ? W1l[n][k] : W1r[n][k-128]
//   i < 26624           : WtB fp32 k-major (128x80) for scalar gemm2
//   else j = i-26624    : pack x row-major -> bf16 (uint4 per 8 floats)
// ---------------------------------------------------------------------------
__global__ __launch_bounds__(256) void prep_kernel(
    const float* __restrict__ W1l, const float* __restrict__ W1r,
    const float* __restrict__ W2l, const float* __restrict__ W2r,
    const float* __restrict__ x, unsigned* __restrict__ WfA,
    float* __restrict__ WtB, unsigned* __restrict__ x_bf16) {
    int i = blockIdx.x * 256 + threadIdx.x;
    if (i < 16384) {
        int f = i >> 8, r = i & 255;
        int lane = r >> 2, u = r & 3;
        int phase = f >> 5, kc = (f >> 3) & 3, nt = f & 7;
        int k0 = phase * 128 + kc * 32 + (lane >> 4) * 8 + u * 2;
        int n = nt * 16 + (lane & 15);
        float w0, w1;
        if (k0 < 128) {
            w0 = W1l[n * 128 + k0];
            w1 = W1l[n * 128 + k0 + 1];
        } else {
            w0 = W1r[n * 128 + k0 - 128];
            w1 = W1r[n * 128 + k0 - 127];
        }
        WfA[i] = bfpack(w0, w1);
    } else if (i < 16384 + 10240) {
        int j = i - 16384;
        int k = j / 80, n = j % 80;
        WtB[j] = (n < 40) ? W2l[n * 128 + k] : W2r[(n - 40) * 128 + k];
    } else {
        int j = i - 26624;
        if (j < 800000) {
            const float4* xf = (const float4*)x;
            float4 a = xf[(size_t)j * 2];
            float4 b = xf[(size_t)j * 2 + 1];
            uint4 o;
            o.x = bfpack(a.x, a.y);
            o.y = bfpack(a.z, a.w);
            o.z = bfpack(b.x, b.y);
            o.w = bfpack(b.z, b.w);
            ((uint4*)x_bf16)[j] = o;
        }
    }
}

// ---------------------------------------------------------------------------
// Gather-mean layer 1 (bf16 x): subgroup-per-node, shuffle-free (R9 proven).
// 16 lanes own a node; 4 edges in flight; fp32 accumulate.
// NOW EMITS bf16 agg1 (uint4 per lane) for the MFMA gemm1.
// ---------------------------------------------------------------------------
__global__ __launch_bounds__(256) void gather1_kernel(const int* __restrict__ csr_src,
                                                      const int* __restrict__ row_ptr,
                                                      const unsigned* __restrict__ x_bf16,
                                                      unsigned* __restrict__ agg1b) {
    int sg = threadIdx.x >> 4;     // 0..15: subgroup = node
    int li = threadIdx.x & 15;     // lane within subgroup
    int gid = blockIdx.x * 16 + sg;
    if (gid >= N_NODES) return;
    int beg = row_ptr[gid], end = row_ptr[gid + 1];
    int n = end - beg;
    const uint4* xb = (const uint4*)x_bf16;  // 16 uint4 per 128-feat row
    float acc[8];
#pragma unroll
    for (int j = 0; j < 8; ++j) acc[j] = 0.f;

    int e = beg;
    for (; e + 3 < end; e += 4) {
        int s0 = csr_src[e], s1 = csr_src[e + 1];
        int s2 = csr_src[e + 2], s3 = csr_src[e + 3];
        uint4 t0 = xb[(size_t)s0 * 16 + li];
        uint4 t1 = xb[(size_t)s1 * 16 + li];
        uint4 t2 = xb[(size_t)s2 * 16 + li];
        uint4 t3 = xb[(size_t)s3 * 16 + li];
        acc[0] += bflo(t0.x) + bflo(t1.x) + bflo(t2.x) + bflo(t3.x);
        acc[1] += bfhi(t0.x) + bfhi(t1.x) + bfhi(t2.x) + bfhi(t3.x);
        acc[2] += bflo(t0.y) + bflo(t1.y) + bflo(t2.y) + bflo(t3.y);
        acc[3] += bfhi(t0.y) + bfhi(t1.y) + bfhi(t2.y) + bfhi(t3.y);
        acc[4] += bflo(t0.z) + bflo(t1.z) + bflo(t2.z) + bflo(t3.z);
        acc[5] += bfhi(t0.z) + bfhi(t1.z) + bfhi(t2.z) + bfhi(t3.z);
        acc[6] += bflo(t0.w) + bflo(t1.w) + bflo(t2.w) + bflo(t3.w);
        acc[7] += bfhi(t0.w) + bfhi(t1.w) + bfhi(t2.w) + bfhi(t3.w);
    }
    for (; e < end; ++e) {
        int s = csr_src[e];
        uint4 t0 = xb[(size_t)s * 16 + li];
        acc[0] += bflo(t0.x); acc[1] += bfhi(t0.x);
        acc[2] += bflo(t0.y); acc[3] += bfhi(t0.y);
        acc[4] += bflo(t0.z); acc[5] += bfhi(t0.z);
        acc[6] += bflo(t0.w); acc[7] += bfhi(t0.w);
    }
    float inv = 1.0f / fmaxf((float)n, 1.0f);
    uint4 o;
    o.x = bfpack(acc[0] * inv, acc[1] * inv);
    o.y = bfpack(acc[2] * inv, acc[3] * inv);
    o.z = bfpack(acc[4] * inv, acc[5] * inv);
    o.w = bfpack(acc[6] * inv, acc[7] * inv);
    ((uint4*)agg1b)[(size_t)gid * 16 + li] = o;
}

// ---------------------------------------------------------------------------
// GEMM1 via MFMA (bf16): h = BN(ReLU(agg1 @ W1l^T + b1 + x @ W1r^T))
// Block = 64 rows x 128 cols; 4 waves x 16-row strip x 8 col-tiles.
// Per phase: A-tile (64x128 bf16) staged in LDS (stride 136 bf16);
// A-frags: 4x ds_read_b128; B-frags: fragment-major global dwordx4 (L2-hot).
// v_mfma_f32_16x16x32_bf16, D layout col=lane&15, row=quad*4+reg.
// ---------------------------------------------------------------------------
__global__ __launch_bounds__(256) void gemm1_kernel(
    const unsigned* __restrict__ agg1b, const unsigned* __restrict__ xb,
    const unsigned* __restrict__ WfA, const float* __restrict__ b1,
    const float* __restrict__ gamma, const float* __restrict__ beta,
    const float* __restrict__ rmean, const float* __restrict__ rvar,
    float* __restrict__ h) {
    __shared__ unsigned Asu[64 * 68];   // 64 rows x 128 bf16, stride 136 bf16
    const int t = threadIdx.x;
    const int wid = __builtin_amdgcn_readfirstlane(t >> 6);
    const int lane = t & 63;
    const int li = lane & 15;
    const int quad = lane >> 4;
    const int mbase = blockIdx.x * 64;

    f32x4 dacc[8];
#pragma unroll
    for (int nt = 0; nt < 8; ++nt) dacc[nt] = (f32x4){0.f, 0.f, 0.f, 0.f};

    for (int phase = 0; phase < 2; ++phase) {
        const unsigned* __restrict__ A = phase ? xb : agg1b;
        __syncthreads();
        // stage 64 rows x 64 uints (coalesced), LDS rows padded to 68 uints
#pragma unroll
        for (int i = 0; i < 4; ++i) {
            int e = i * 256 + t;
            int row = e >> 4, seg = e & 15;
            int rr = mbase + row;
            rr = (rr < N_NODES) ? rr : N_NODES - 1;
            uint4 v = ((const uint4*)A)[(size_t)rr * 16 + seg];
            *(uint4*)&Asu[row * 68 + seg * 4] = v;
        }
        __syncthreads();
        // A fragments: row = wid*16 + li, k = kc*32 + quad*8 (+0..7)
        bf16x8 af[4];
#pragma unroll
        for (int kc = 0; kc < 4; ++kc)
            af[kc] = *(const bf16x8*)&Asu[(wid * 16 + li) * 68 + kc * 16 + quad * 4];

        const unsigned* __restrict__ Wp = WfA + phase * 8192;
#pragma unroll
        for (int nt = 0; nt < 8; ++nt) {
#pragma unroll
            for (int kc = 0; kc < 4; ++kc) {
                bf16x8 bfr = *(const bf16x8*)(Wp + (size_t)(kc * 8 + nt) * 256 + lane * 4);
                dacc[nt] = __builtin_amdgcn_mfma_f32_16x16x32_bf16(af[kc], bfr, dacc[nt], 0, 0, 0);
            }
        }
    }

    // epilogue: bias + ReLU + BN; D element (nt, r) -> row = quad*4+r, col = nt*16+li
#pragma unroll
    for (int nt = 0; nt < 8; ++nt) {
        int cg = nt * 16 + li;
        float sc = gamma[cg] * rsqrtf(rvar[cg] + BN_EPS);
        float sh = fmaf(-rmean[cg], sc, beta[cg]);
        float bb = b1[cg];
#pragma unroll
        for (int r = 0; r < 4; ++r) {
            int row = mbase + wid * 16 + quad * 4 + r;
            if (row < N_NODES) {
                float pre = dacc[nt][r] + bb;
                h[(size_t)row * 128 + cg] = fmaf(fmaxf(pre, 0.f), sc, sh);
            }
        }
    }
}

// ---------------------------------------------------------------------------
// GEMM2 (R6 scalar structure, proven): [z2 | p2] = h @ WtB. 64 rows x 80
// cols, 4 waves x 20 cols (acc[20]), s_load weights, outputs via LDS.
// z2 packed bf16 stride 40 (80 B/row); p2 fp32 stride 40.
// ---------------------------------------------------------------------------
__global__ __launch_bounds__(256) void gemm2_kernel(const float* __restrict__ h,
                                                    const float* __restrict__ WtB,
                                                    unsigned* __restrict__ z2b,
                                                    float* __restrict__ p2) {
    __shared__ float As[64][129];
    const int t = threadIdx.x;
    const int wid = __builtin_amdgcn_readfirstlane(t >> 6);
    const int lane = t & 63;
    const int mbase = blockIdx.x * 64;
    const int c0 = wid * 20;

    float acc[20];
#pragma unroll
    for (int c = 0; c < 20; ++c) acc[c] = 0.f;

#pragma unroll
    for (int i = 0; i < 8; ++i) {
        int e = i * 256 + t;
        int r = e >> 5, k4 = e & 31;
        int rr = mbase + r;
        rr = (rr < N_NODES) ? rr : N_NODES - 1;
        float4 v = ((const float4*)h)[(size_t)rr * 32 + k4];
        *(float4*)&As[r][k4 * 4] = v;
    }
    __syncthreads();
#pragma unroll 4
    for (int k4 = 0; k4 < 32; ++k4) {
        float4 a4 = *(const float4*)&As[lane][k4 * 4];
#pragma unroll
        for (int j = 0; j < 4; ++j) {
            float av = (j == 0) ? a4.x : (j == 1) ? a4.y : (j == 2) ? a4.z : a4.w;
            const float* __restrict__ Wr = WtB + (size_t)(k4 * 4 + j) * 80 + c0;
#pragma unroll
            for (int c = 0; c < 20; ++c) acc[c] = fmaf(av, Wr[c], acc[c]);
        }
    }

    __syncthreads();
#pragma unroll
    for (int c = 0; c < 20; ++c) As[lane][c0 + c] = acc[c];
    __syncthreads();

    // z2 bf16: 64 rows x 10 uint2
    for (int e = t; e < 640; e += 256) {
        int r = e / 10, q = e - r * 10;
        if (mbase + r < N_NODES) {
            float4 v = *(const float4*)&As[r][q * 4];
            uint2 o;
            o.x = bfpack(v.x, v.y);
            o.y = bfpack(v.z, v.w);
            ((uint2*)z2b)[(size_t)(mbase + r) * 10 + q] = o;
        }
    }
    // p2 fp32: 64 rows x 10 float4 (cols 40..79)
    for (int e = t; e < 640; e += 256) {
        int r = e / 10, q = e - r * 10;
        if (mbase + r < N_NODES) {
            float4 v = *(const float4*)&As[r][40 + q * 4];
            *(float4*)(p2 + (size_t)(mbase + r) * 40 + q * 4) = v;
        }
    }
}

// ---------------------------------------------------------------------------
// Gather layer 2 + final (bf16 z2): subgroup-per-node, shuffle-free (R9).
// 10 lanes own a node; 25 subgroups/block; 4 edges in flight.
// ---------------------------------------------------------------------------
__global__ __launch_bounds__(256) void gather2_kernel(const int* __restrict__ csr_src,
                                                      const int* __restrict__ row_ptr,
                                                      const unsigned* __restrict__ z2b,
                                                      const float* __restrict__ p2,
                                                      const float* __restrict__ b2,
                                                      float* __restrict__ out) {
    int t = threadIdx.x;
    int sub = t / 10;             // 0..25 (25 = idle)
    int li = t - sub * 10;        // 0..9
    if (sub >= 25) return;
    int gid = blockIdx.x * 25 + sub;
    if (gid >= N_NODES) return;
    int beg = row_ptr[gid], end = row_ptr[gid + 1];
    int n = end - beg;
    const uint2* z2 = (const uint2*)z2b;  // 10 uint2 per row
    float4 acc = {0.f, 0.f, 0.f, 0.f};
    int e = beg;
    for (; e + 3 < end; e += 4) {
        int s0 = csr_src[e], s1 = csr_src[e + 1];
        int s2 = csr_src[e + 2], s3 = csr_src[e + 3];
        uint2 t0 = z2[(size_t)s0 * 10 + li];
        uint2 t1 = z2[(size_t)s1 * 10 + li];
        uint2 t2 = z2[(size_t)s2 * 10 + li];
        uint2 t3 = z2[(size_t)s3 * 10 + li];
        acc.x += bflo(t0.x) + bflo(t1.x) + bflo(t2.x) + bflo(t3.x);
        acc.y += bfhi(t0.x) + bfhi(t1.x) + bfhi(t2.x) + bfhi(t3.x);
        acc.z += bflo(t0.y) + bflo(t1.y) + bflo(t2.y) + bflo(t3.y);
        acc.w += bfhi(t0.y) + bfhi(t1.y) + bfhi(t2.y) + bfhi(t3.y);
    }
    for (; e < end; ++e) {
        int s = csr_src[e];
        uint2 t0 = z2[(size_t)s * 10 + li];
        acc.x += bflo(t0.x); acc.y += bfhi(t0.x);
        acc.z += bflo(t0.y); acc.w += bfhi(t0.y);
    }
    float inv = 1.0f / fmaxf((float)n, 1.0f);
    float4 p = ((const float4*)p2)[(size_t)gid * 10 + li];
    float4 bb = ((const float4*)b2)[li];
    float4 r;
    r.x = fmaf(acc.x, inv, p.x + bb.x);
    r.y = fmaf(acc.y, inv, p.y + bb.y);
    r.z = fmaf(acc.z, inv, p.z + bb.z);
    r.w = fmaf(acc.w, inv, p.w + bb.w);
    ((float4*)out)[(size_t)gid * 10 + li] = r;
}

// ---------------------------------------------------------------------------
// Launch. ws layout:
//   int  deg_i[50048], cursor[50048]          (memset 0 together)
//   int  row_ptr[50052], blk_sum[256], blk_off[256], csr_src[800000]
//   u32  WfA[16384]                           (fragment-major bf16 W1)
//   f32  WtB[10240]
//   u32  x_bf16[3200000]
//   u32  agg1b[50048*64]   -- z2b[50048*20] + p2[50048*40 f32] alias it
//   f32  h[50048*128]
// ---------------------------------------------------------------------------
extern "C" void kernel_launch(void* const* d_in, const int* in_sizes, int n_in,
                              void* d_out, int out_size, void* d_ws, size_t ws_size,
                              hipStream_t stream) {
    const float* x     = (const float*)d_in[0];
    const int*   ei    = (const int*)d_in[1];
    const float* W1l   = (const float*)d_in[2];
    const float* b1    = (const float*)d_in[3];
    const float* W1r   = (const float*)d_in[4];
    const float* gamma = (const float*)d_in[5];
    const float* beta  = (const float*)d_in[6];
    const float* rmean = (const float*)d_in[7];
    const float* rvar  = (const float*)d_in[8];
    const float* W2l   = (const float*)d_in[9];
    const float* b2    = (const float*)d_in[10];
    const float* W2r   = (const float*)d_in[11];
    float* out = (float*)d_out;

    int* deg_i       = (int*)d_ws;
    int* cursor      = deg_i + 50048;
    int* row_ptr     = cursor + 50048;
    int* blk_sum     = row_ptr + 50052;
    int* blk_off     = blk_sum + 256;
    int* csr_src     = blk_off + 256;
    unsigned* WfA    = (unsigned*)(csr_src + 800000);
    float* WtB       = (float*)(WfA + 16384);
    unsigned* x_bf16 = (unsigned*)(WtB + 10240);
    unsigned* agg1b  = x_bf16 + 3200000;
    unsigned* z2b    = agg1b;                       // alias (agg1b dead after gemm1)
    float* p2        = (float*)(agg1b + 50048 * 20);
    float* h         = (float*)(agg1b + (size_t)50048 * 64);

    const int* src = ei;
    const int* dst = ei + N_EDGES;

    hipMemsetAsync(deg_i, 0, (size_t)(50048 + 50048) * sizeof(int), stream);

    deg_kernel<<<(N_EDGES + 255) / 256, 256, 0, stream>>>(dst, deg_i);
    scanA_kernel<<<SCAN_BLOCKS, 256, 0, stream>>>(deg_i, row_ptr, blk_sum);
    scanB_kernel<<<1, 256, 0, stream>>>(blk_sum, blk_off);
    scanC_kernel<<<SCAN_BLOCKS, 256, 0, stream>>>(row_ptr, blk_off);
    fill_kernel<<<(N_EDGES + 255) / 256, 256, 0, stream>>>(src, dst, row_ptr, cursor, csr_src);

    prep_kernel<<<(26624 + 800000 + 255) / 256, 256, 0, stream>>>(W1l, W1r, W2l, W2r,
                                                                  x, WfA, WtB, x_bf16);

    gather1_kernel<<<(N_NODES + 15) / 16, 256, 0, stream>>>(csr_src, row_ptr, x_bf16, agg1b);

    gemm1_kernel<<<(N_NODES + 63) / 64, 256, 0, stream>>>(agg1b, x_bf16, WfA, b1, gamma,
                                                          beta, rmean, rvar, h);

    gemm2_kernel<<<(N_NODES + 63) / 64, 256, 0, stream>>>(h, WtB, z2b, p2);

    gather2_kernel<<<(N_NODES + 24) / 25, 256, 0, stream>>>(csr_src, row_ptr, z2b, p2, b2, out);
}

// Round 11
// 261.611 us; speedup vs baseline: 2.1939x; 1.0581x over previous
//
#include <hip/hip_runtime.h>

#define N_NODES 50000
#define N_EDGES 800000
#define N_FEAT 128
#define N_HID 128
#define N_CLS 40
#define BN_EPS 1e-5f

#define SCAN_BLOCKS ((N_NODES + 255) / 256)  // 196

typedef short bf16x8 __attribute__((ext_vector_type(8)));
typedef float f32x4 __attribute__((ext_vector_type(4)));

// RNE float->bf16 helpers
__device__ __forceinline__ unsigned bfpack(float a, float b) {
    unsigned ua = __float_as_uint(a), ub = __float_as_uint(b);
    ua = (ua + 0x7FFFu + ((ua >> 16) & 1u)) >> 16;
    ub = (ub + 0x7FFFu + ((ub >> 16) & 1u)) >> 16;
    return ua | (ub << 16);
}
__device__ __forceinline__ unsigned short bfr1(float a) {
    unsigned u = __float_as_uint(a);
    u = (u + 0x7FFFu + ((u >> 16) & 1u)) >> 16;
    return (unsigned short)u;
}
__device__ __forceinline__ float bflo(unsigned u) { return __uint_as_float(u << 16); }
__device__ __forceinline__ float bfhi(unsigned u) { return __uint_as_float(u & 0xFFFF0000u); }

// ---------------------------------------------------------------------------
// K1: int degree histogram.
// ---------------------------------------------------------------------------
__global__ __launch_bounds__(256) void deg_kernel(const int* __restrict__ dst,
                                                  int* __restrict__ deg_i) {
    int e = blockIdx.x * 256 + threadIdx.x;
    if (e < N_EDGES) atomicAdd(&deg_i[dst[e]], 1);
}

// ---------------------------------------------------------------------------
// Scan A/B/C: row_ptr = exclusive scan of degrees. scanC also seeds cursor
// with the absolute start offsets (fill's atomic then returns absolute pos).
// ---------------------------------------------------------------------------
__global__ __launch_bounds__(256) void scanA_kernel(const int* __restrict__ deg_i,
                                                    int* __restrict__ row_ptr,
                                                    int* __restrict__ blk_sum) {
    __shared__ int tmp[256];
    int t = threadIdx.x;
    int i = blockIdx.x * 256 + t;
    int v = (i < N_NODES) ? deg_i[i] : 0;
    tmp[t] = v;
    __syncthreads();
    for (int off = 1; off < 256; off <<= 1) {
        int a = (t >= off) ? tmp[t - off] : 0;
        __syncthreads();
        if (t >= off) tmp[t] += a;
        __syncthreads();
    }
    if (i < N_NODES) row_ptr[i] = tmp[t] - v;
    if (t == 255) blk_sum[blockIdx.x] = tmp[255];
}

__global__ __launch_bounds__(256) void scanB_kernel(const int* __restrict__ blk_sum,
                                                    int* __restrict__ blk_off) {
    __shared__ int tmp[256];
    int t = threadIdx.x;
    int v = (t < SCAN_BLOCKS) ? blk_sum[t] : 0;
    tmp[t] = v;
    __syncthreads();
    for (int off = 1; off < 256; off <<= 1) {
        int a = (t >= off) ? tmp[t - off] : 0;
        __syncthreads();
        if (t >= off) tmp[t] += a;
        __syncthreads();
    }
    if (t < SCAN_BLOCKS) blk_off[t] = tmp[t] - v;
}

__global__ __launch_bounds__(256) void scanC_kernel(int* __restrict__ row_ptr,
                                                    int* __restrict__ cursor,
                                                    const int* __restrict__ blk_off) {
    int i = blockIdx.x * 256 + threadIdx.x;
    if (i < N_NODES) {
        int v = row_ptr[i] + blk_off[blockIdx.x];
        row_ptr[i] = v;
        cursor[i] = v;
    }
    if (i == 0) row_ptr[N_NODES] = N_EDGES;
}

// ---------------------------------------------------------------------------
// CSR fill: ushort payload (node ids < 65536), absolute cursor.
// ---------------------------------------------------------------------------
__global__ __launch_bounds__(256) void fill_kernel(const int* __restrict__ src,
                                                   const int* __restrict__ dst,
                                                   int* __restrict__ cursor,
                                                   unsigned short* __restrict__ csr16) {
    int e = blockIdx.x * 256 + threadIdx.x;
    if (e >= N_EDGES) return;
    int pos = atomicAdd(&cursor[dst[e]], 1);
    csr16[pos] = (unsigned short)src[e];
}

// ---------------------------------------------------------------------------
// Prep:
//   i < 16384   : WfA fragment-major bf16 W1 (f = phase*32 + kc*8 + nt)
//   i < 21504   : WfB fragment-major bf16 W2 (f = kc*5 + nt), n<40 W2l else W2r
//   else        : pack x row-major -> bf16 (uint4 per 8 floats)
// Fragment layout (both): within frag, uint r: lane=r>>2, u=r&3,
//   k0 = kbase + (lane>>4)*8 + u*2, n = nt*16 + (lane&15),
//   val = pack(w(k0,n), w(k0+1,n)).
// ---------------------------------------------------------------------------
__global__ __launch_bounds__(256) void prep_kernel(
    const float* __restrict__ W1l, const float* __restrict__ W1r,
    const float* __restrict__ W2l, const float* __restrict__ W2r,
    const float* __restrict__ x, unsigned* __restrict__ WfA,
    unsigned* __restrict__ WfB, unsigned* __restrict__ x_bf16) {
    int i = blockIdx.x * 256 + threadIdx.x;
    if (i < 16384) {
        int f = i >> 8, r = i & 255;
        int lane = r >> 2, u = r & 3;
        int phase = f >> 5, kc = (f >> 3) & 3, nt = f & 7;
        int k0 = phase * 128 + kc * 32 + (lane >> 4) * 8 + u * 2;
        int n = nt * 16 + (lane & 15);
        float w0, w1;
        if (k0 < 128) {
            w0 = W1l[n * 128 + k0];
            w1 = W1l[n * 128 + k0 + 1];
        } else {
            w0 = W1r[n * 128 + k0 - 128];
            w1 = W1r[n * 128 + k0 - 127];
        }
        WfA[i] = bfpack(w0, w1);
    } else if (i < 21504) {
        int j = i - 16384;
        int f = j >> 8, r = j & 255;
        int lane = r >> 2, u = r & 3;
        int kc = f / 5, nt = f % 5;
        int k0 = kc * 32 + (lane >> 4) * 8 + u * 2;
        int n = nt * 16 + (lane & 15);
        float w0, w1;
        if (n < 40) {
            w0 = W2l[n * 128 + k0];
            w1 = W2l[n * 128 + k0 + 1];
        } else {
            w0 = W2r[(n - 40) * 128 + k0];
            w1 = W2r[(n - 40) * 128 + k0 + 1];
        }
        WfB[j] = bfpack(w0, w1);
    } else {
        int j = i - 21504;
        if (j < 800000) {
            const float4* xf = (const float4*)x;
            float4 a = xf[(size_t)j * 2];
            float4 b = xf[(size_t)j * 2 + 1];
            uint4 o;
            o.x = bfpack(a.x, a.y);
            o.y = bfpack(a.z, a.w);
            o.z = bfpack(b.x, b.y);
            o.w = bfpack(b.z, b.w);
            ((uint4*)x_bf16)[j] = o;
        }
    }
}

// ---------------------------------------------------------------------------
// Gather-mean layer 1 (bf16 x): subgroup-per-node, shuffle-free.
// 16 lanes own a node; 4 edges in flight; fp32 accumulate; emits bf16 agg1.
// ---------------------------------------------------------------------------
__global__ __launch_bounds__(256) void gather1_kernel(const unsigned short* __restrict__ csr16,
                                                      const int* __restrict__ row_ptr,
                                                      const unsigned* __restrict__ x_bf16,
                                                      unsigned* __restrict__ agg1b) {
    int sg = threadIdx.x >> 4;
    int li = threadIdx.x & 15;
    int gid = blockIdx.x * 16 + sg;
    if (gid >= N_NODES) return;
    int beg = row_ptr[gid], end = row_ptr[gid + 1];
    int n = end - beg;
    const uint4* xb = (const uint4*)x_bf16;
    float acc[8];
#pragma unroll
    for (int j = 0; j < 8; ++j) acc[j] = 0.f;

    int e = beg;
    for (; e + 3 < end; e += 4) {
        int s0 = csr16[e], s1 = csr16[e + 1];
        int s2 = csr16[e + 2], s3 = csr16[e + 3];
        uint4 t0 = xb[(size_t)s0 * 16 + li];
        uint4 t1 = xb[(size_t)s1 * 16 + li];
        uint4 t2 = xb[(size_t)s2 * 16 + li];
        uint4 t3 = xb[(size_t)s3 * 16 + li];
        acc[0] += bflo(t0.x) + bflo(t1.x) + bflo(t2.x) + bflo(t3.x);
        acc[1] += bfhi(t0.x) + bfhi(t1.x) + bfhi(t2.x) + bfhi(t3.x);
        acc[2] += bflo(t0.y) + bflo(t1.y) + bflo(t2.y) + bflo(t3.y);
        acc[3] += bfhi(t0.y) + bfhi(t1.y) + bfhi(t2.y) + bfhi(t3.y);
        acc[4] += bflo(t0.z) + bflo(t1.z) + bflo(t2.z) + bflo(t3.z);
        acc[5] += bfhi(t0.z) + bfhi(t1.z) + bfhi(t2.z) + bfhi(t3.z);
        acc[6] += bflo(t0.w) + bflo(t1.w) + bflo(t2.w) + bflo(t3.w);
        acc[7] += bfhi(t0.w) + bfhi(t1.w) + bfhi(t2.w) + bfhi(t3.w);
    }
    for (; e < end; ++e) {
        int s = csr16[e];
        uint4 t0 = xb[(size_t)s * 16 + li];
        acc[0] += bflo(t0.x); acc[1] += bfhi(t0.x);
        acc[2] += bflo(t0.y); acc[3] += bfhi(t0.y);
        acc[4] += bflo(t0.z); acc[5] += bfhi(t0.z);
        acc[6] += bflo(t0.w); acc[7] += bfhi(t0.w);
    }
    float inv = 1.0f / fmaxf((float)n, 1.0f);
    uint4 o;
    o.x = bfpack(acc[0] * inv, acc[1] * inv);
    o.y = bfpack(acc[2] * inv, acc[3] * inv);
    o.z = bfpack(acc[4] * inv, acc[5] * inv);
    o.w = bfpack(acc[6] * inv, acc[7] * inv);
    ((uint4*)agg1b)[(size_t)gid * 16 + li] = o;
}

// ---------------------------------------------------------------------------
// GEMM1 via MFMA (bf16): h = BN(ReLU(agg1 @ W1l^T + b1 + x @ W1r^T))
// 64 rows x 128 cols; 4 waves x 16-row strip x 8 n-tiles; A staged in LDS
// (stride 68 uints); B frags fragment-major global (L2-hot).
// NOW EMITS h AS bf16 (ushort scalar stores) for the MFMA gemm2.
// ---------------------------------------------------------------------------
__global__ __launch_bounds__(256) void gemm1_kernel(
    const unsigned* __restrict__ agg1b, const unsigned* __restrict__ xb,
    const unsigned* __restrict__ WfA, const float* __restrict__ b1,
    const float* __restrict__ gamma, const float* __restrict__ beta,
    const float* __restrict__ rmean, const float* __restrict__ rvar,
    unsigned short* __restrict__ hb) {
    __shared__ unsigned Asu[64 * 68];
    const int t = threadIdx.x;
    const int wid = __builtin_amdgcn_readfirstlane(t >> 6);
    const int lane = t & 63;
    const int li = lane & 15;
    const int quad = lane >> 4;
    const int mbase = blockIdx.x * 64;

    f32x4 dacc[8];
#pragma unroll
    for (int nt = 0; nt < 8; ++nt) dacc[nt] = (f32x4){0.f, 0.f, 0.f, 0.f};

    for (int phase = 0; phase < 2; ++phase) {
        const unsigned* __restrict__ A = phase ? xb : agg1b;
        __syncthreads();
#pragma unroll
        for (int i = 0; i < 4; ++i) {
            int e = i * 256 + t;
            int row = e >> 4, seg = e & 15;
            int rr = mbase + row;
            rr = (rr < N_NODES) ? rr : N_NODES - 1;
            uint4 v = ((const uint4*)A)[(size_t)rr * 16 + seg];
            *(uint4*)&Asu[row * 68 + seg * 4] = v;
        }
        __syncthreads();
        bf16x8 af[4];
#pragma unroll
        for (int kc = 0; kc < 4; ++kc)
            af[kc] = *(const bf16x8*)&Asu[(wid * 16 + li) * 68 + kc * 16 + quad * 4];

        const unsigned* __restrict__ Wp = WfA + phase * 8192;
#pragma unroll
        for (int nt = 0; nt < 8; ++nt) {
#pragma unroll
            for (int kc = 0; kc < 4; ++kc) {
                bf16x8 bfr = *(const bf16x8*)(Wp + (size_t)(kc * 8 + nt) * 256 + lane * 4);
                dacc[nt] = __builtin_amdgcn_mfma_f32_16x16x32_bf16(af[kc], bfr, dacc[nt], 0, 0, 0);
            }
        }
    }

#pragma unroll
    for (int nt = 0; nt < 8; ++nt) {
        int cg = nt * 16 + li;
        float sc = gamma[cg] * rsqrtf(rvar[cg] + BN_EPS);
        float sh = fmaf(-rmean[cg], sc, beta[cg]);
        float bb = b1[cg];
#pragma unroll
        for (int r = 0; r < 4; ++r) {
            int row = mbase + wid * 16 + quad * 4 + r;
            if (row < N_NODES) {
                float pre = dacc[nt][r] + bb;
                hb[(size_t)row * 128 + cg] = bfr1(fmaf(fmaxf(pre, 0.f), sc, sh));
            }
        }
    }
}

// ---------------------------------------------------------------------------
// GEMM2 via MFMA (bf16): [z2 | p2] = h @ [W2l^T | W2r^T]  (80 cols, 5 n-tiles)
// Same structure as gemm1; h (bf16) staged once in LDS; 20 MFMA/wave.
// z2 bf16 (stride 40 ushorts), p2 fp32 (stride 40).
// ---------------------------------------------------------------------------
__global__ __launch_bounds__(256) void gemm2_kernel(const unsigned short* __restrict__ hb,
                                                    const unsigned* __restrict__ WfB,
                                                    unsigned short* __restrict__ z2s,
                                                    float* __restrict__ p2) {
    __shared__ unsigned Asu[64 * 68];
    const int t = threadIdx.x;
    const int wid = __builtin_amdgcn_readfirstlane(t >> 6);
    const int lane = t & 63;
    const int li = lane & 15;
    const int quad = lane >> 4;
    const int mbase = blockIdx.x * 64;

    f32x4 dacc[5];
#pragma unroll
    for (int nt = 0; nt < 5; ++nt) dacc[nt] = (f32x4){0.f, 0.f, 0.f, 0.f};

#pragma unroll
    for (int i = 0; i < 4; ++i) {
        int e = i * 256 + t;
        int row = e >> 4, seg = e & 15;
        int rr = mbase + row;
        rr = (rr < N_NODES) ? rr : N_NODES - 1;
        uint4 v = ((const uint4*)hb)[(size_t)rr * 16 + seg];
        *(uint4*)&Asu[row * 68 + seg * 4] = v;
    }
    __syncthreads();
    bf16x8 af[4];
#pragma unroll
    for (int kc = 0; kc < 4; ++kc)
        af[kc] = *(const bf16x8*)&Asu[(wid * 16 + li) * 68 + kc * 16 + quad * 4];

#pragma unroll
    for (int nt = 0; nt < 5; ++nt) {
#pragma unroll
        for (int kc = 0; kc < 4; ++kc) {
            bf16x8 bfr = *(const bf16x8*)(WfB + (size_t)(kc * 5 + nt) * 256 + lane * 4);
            dacc[nt] = __builtin_amdgcn_mfma_f32_16x16x32_bf16(af[kc], bfr, dacc[nt], 0, 0, 0);
        }
    }

#pragma unroll
    for (int nt = 0; nt < 5; ++nt) {
        int cg = nt * 16 + li;
#pragma unroll
        for (int r = 0; r < 4; ++r) {
            int row = mbase + wid * 16 + quad * 4 + r;
            if (row < N_NODES) {
                float v = dacc[nt][r];
                if (cg < 40) z2s[(size_t)row * 40 + cg] = bfr1(v);
                else p2[(size_t)row * 40 + (cg - 40)] = v;
            }
        }
    }
}

// ---------------------------------------------------------------------------
// Gather layer 2 + final (bf16 z2): subgroup-per-node, shuffle-free.
// 10 lanes own a node; 25 subgroups/block; 4 edges in flight.
// ---------------------------------------------------------------------------
__global__ __launch_bounds__(256) void gather2_kernel(const unsigned short* __restrict__ csr16,
                                                      const int* __restrict__ row_ptr,
                                                      const unsigned short* __restrict__ z2s,
                                                      const float* __restrict__ p2,
                                                      const float* __restrict__ b2,
                                                      float* __restrict__ out) {
    int t = threadIdx.x;
    int sub = t / 10;
    int li = t - sub * 10;
    if (sub >= 25) return;
    int gid = blockIdx.x * 25 + sub;
    if (gid >= N_NODES) return;
    int beg = row_ptr[gid], end = row_ptr[gid + 1];
    int n = end - beg;
    const uint2* z2 = (const uint2*)z2s;  // 10 uint2 per row
    float4 acc = {0.f, 0.f, 0.f, 0.f};
    int e = beg;
    for (; e + 3 < end; e += 4) {
        int s0 = csr16[e], s1 = csr16[e + 1];
        int s2 = csr16[e + 2], s3 = csr16[e + 3];
        uint2 t0 = z2[(size_t)s0 * 10 + li];
        uint2 t1 = z2[(size_t)s1 * 10 + li];
        uint2 t2 = z2[(size_t)s2 * 10 + li];
        uint2 t3 = z2[(size_t)s3 * 10 + li];
        acc.x += bflo(t0.x) + bflo(t1.x) + bflo(t2.x) + bflo(t3.x);
        acc.y += bfhi(t0.x) + bfhi(t1.x) + bfhi(t2.x) + bfhi(t3.x);
        acc.z += bflo(t0.y) + bflo(t1.y) + bflo(t2.y) + bflo(t3.y);
        acc.w += bfhi(t0.y) + bfhi(t1.y) + bfhi(t2.y) + bfhi(t3.y);
    }
    for (; e < end; ++e) {
        int s = csr16[e];
        uint2 t0 = z2[(size_t)s * 10 + li];
        acc.x += bflo(t0.x); acc.y += bfhi(t0.x);
        acc.z += bflo(t0.y); acc.w += bfhi(t0.y);
    }
    float inv = 1.0f / fmaxf((float)n, 1.0f);
    float4 p = ((const float4*)p2)[(size_t)gid * 10 + li];
    float4 bb = ((const float4*)b2)[li];
    float4 r;
    r.x = fmaf(acc.x, inv, p.x + bb.x);
    r.y = fmaf(acc.y, inv, p.y + bb.y);
    r.z = fmaf(acc.z, inv, p.z + bb.z);
    r.w = fmaf(acc.w, inv, p.w + bb.w);
    ((float4*)out)[(size_t)gid * 10 + li] = r;
}

// ---------------------------------------------------------------------------
// Launch. ws layout (int units):
//   deg_i[50048] (memset 0), cursor[50048] (seeded by scanC),
//   row_ptr[50052], blk_sum[256], blk_off[256]
//   csr16  ushort[800000] (= 400000 ints)
//   WfA u32[16384], WfB u32[5120]
//   x_bf16 u32[3200000]
//   agg1b u32[50048*64]  -- z2s ushort[50048*40] + p2 f32[50048*40] alias it
//   hb ushort[50048*128] (= 50048*64 u32)
// ---------------------------------------------------------------------------
extern "C" void kernel_launch(void* const* d_in, const int* in_sizes, int n_in,
                              void* d_out, int out_size, void* d_ws, size_t ws_size,
                              hipStream_t stream) {
    const float* x     = (const float*)d_in[0];
    const int*   ei    = (const int*)d_in[1];
    const float* W1l   = (const float*)d_in[2];
    const float* b1    = (const float*)d_in[3];
    const float* W1r   = (const float*)d_in[4];
    const float* gamma = (const float*)d_in[5];
    const float* beta  = (const float*)d_in[6];
    const float* rmean = (const float*)d_in[7];
    const float* rvar  = (const float*)d_in[8];
    const float* W2l   = (const float*)d_in[9];
    const float* b2    = (const float*)d_in[10];
    const float* W2r   = (const float*)d_in[11];
    float* out = (float*)d_out;

    int* deg_i            = (int*)d_ws;
    int* cursor           = deg_i + 50048;
    int* row_ptr          = cursor + 50048;
    int* blk_sum          = row_ptr + 50052;
    int* blk_off          = blk_sum + 256;
    unsigned short* csr16 = (unsigned short*)(blk_off + 256);
    unsigned* WfA         = (unsigned*)((int*)(blk_off + 256) + 400000);
    unsigned* WfB         = WfA + 16384;
    unsigned* x_bf16      = WfB + 5120;
    unsigned* agg1b       = x_bf16 + 3200000;
    unsigned short* z2s   = (unsigned short*)agg1b;     // alias (agg1b dead after gemm1)
    float* p2             = (float*)(agg1b + 50048 * 20);
    unsigned short* hb    = (unsigned short*)(agg1b + (size_t)50048 * 64);

    const int* src = ei;
    const int* dst = ei + N_EDGES;

    hipMemsetAsync(deg_i, 0, (size_t)50048 * sizeof(int), stream);

    deg_kernel<<<(N_EDGES + 255) / 256, 256, 0, stream>>>(dst, deg_i);
    scanA_kernel<<<SCAN_BLOCKS, 256, 0, stream>>>(deg_i, row_ptr, blk_sum);
    scanB_kernel<<<1, 256, 0, stream>>>(blk_sum, blk_off);
    scanC_kernel<<<SCAN_BLOCKS, 256, 0, stream>>>(row_ptr, cursor, blk_off);
    fill_kernel<<<(N_EDGES + 255) / 256, 256, 0, stream>>>(src, dst, cursor, csr16);

    prep_kernel<<<(21504 + 800000 + 255) / 256, 256, 0, stream>>>(W1l, W1r, W2l, W2r,
                                                                  x, WfA, WfB, x_bf16);

    gather1_kernel<<<(N_NODES + 15) / 16, 256, 0, stream>>>(csr16, row_ptr, x_bf16, agg1b);

    gemm1_kernel<<<(N_NODES + 63) / 64, 256, 0, stream>>>(agg1b, x_bf16, WfA, b1, gamma,
                                                          beta, rmean, rvar, hb);

    gemm2_kernel<<<(N_NODES + 63) / 64, 256, 0, stream>>>(hb, WfB, z2s, p2);

    gather2_kernel<<<(N_NODES + 24) / 25, 256, 0, stream>>>(csr16, row_ptr, z2s, p2, b2, out);
}

// Round 12
// 257.830 us; speedup vs baseline: 2.2260x; 1.0147x over previous
//
#include <hip/hip_runtime.h>

#define N_NODES 50000
#define N_EDGES 800000
#define N_FEAT 128
#define N_HID 128
#define N_CLS 40
#define BN_EPS 1e-5f

#define SCAN_BLOCKS ((N_NODES + 255) / 256)  // 196
#define EDGE_T 200192                        // 782 blocks * 256 (4 edges/thread)

typedef short bf16x8 __attribute__((ext_vector_type(8)));
typedef float f32x4 __attribute__((ext_vector_type(4)));

// RNE float->bf16 helpers
__device__ __forceinline__ unsigned bfpack(float a, float b) {
    unsigned ua = __float_as_uint(a), ub = __float_as_uint(b);
    ua = (ua + 0x7FFFu + ((ua >> 16) & 1u)) >> 16;
    ub = (ub + 0x7FFFu + ((ub >> 16) & 1u)) >> 16;
    return ua | (ub << 16);
}
__device__ __forceinline__ unsigned short bfr1(float a) {
    unsigned u = __float_as_uint(a);
    u = (u + 0x7FFFu + ((u >> 16) & 1u)) >> 16;
    return (unsigned short)u;
}
__device__ __forceinline__ float bflo(unsigned u) { return __uint_as_float(u << 16); }
__device__ __forceinline__ float bfhi(unsigned u) { return __uint_as_float(u & 0xFFFF0000u); }

// ---------------------------------------------------------------------------
// K1: degree histogram, 4 edges/thread (fire-and-forget atomics).
// ---------------------------------------------------------------------------
__global__ __launch_bounds__(256) void deg_kernel(const int* __restrict__ dst,
                                                  int* __restrict__ deg_i) {
    int tid = blockIdx.x * 256 + threadIdx.x;
    int d0 = dst[tid];
    int d1 = dst[tid + EDGE_T];
    int d2 = dst[tid + 2 * EDGE_T];
    int e3 = tid + 3 * EDGE_T;
    atomicAdd(&deg_i[d0], 1);
    atomicAdd(&deg_i[d1], 1);
    atomicAdd(&deg_i[d2], 1);
    if (e3 < N_EDGES) atomicAdd(&deg_i[dst[e3]], 1);
}

// ---------------------------------------------------------------------------
// scanA: per-block exclusive scan of degrees; block totals out.
// ---------------------------------------------------------------------------
__global__ __launch_bounds__(256) void scanA_kernel(const int* __restrict__ deg_i,
                                                    int* __restrict__ row_ptr,
                                                    int* __restrict__ blk_sum) {
    __shared__ int tmp[256];
    int t = threadIdx.x;
    int i = blockIdx.x * 256 + t;
    int v = (i < N_NODES) ? deg_i[i] : 0;
    tmp[t] = v;
    __syncthreads();
    for (int off = 1; off < 256; off <<= 1) {
        int a = (t >= off) ? tmp[t - off] : 0;
        __syncthreads();
        if (t >= off) tmp[t] += a;
        __syncthreads();
    }
    if (i < N_NODES) row_ptr[i] = tmp[t] - v;
    if (t == 255) blk_sum[blockIdx.x] = tmp[255];
}

// ---------------------------------------------------------------------------
// scanC (fused scanB): each block reduces blk_sum[0..bid-1] itself (196<=256),
// then applies the offset and seeds cursor with absolute start positions.
// ---------------------------------------------------------------------------
__global__ __launch_bounds__(256) void scanC_kernel(int* __restrict__ row_ptr,
                                                    int* __restrict__ cursor,
                                                    const int* __restrict__ blk_sum) {
    __shared__ int wsum[4];
    int t = threadIdx.x;
    int v = (t < blockIdx.x && t < SCAN_BLOCKS) ? blk_sum[t] : 0;
    int s = v;
#pragma unroll
    for (int o = 32; o > 0; o >>= 1) s += __shfl_down(s, o);
    if ((t & 63) == 0) wsum[t >> 6] = s;
    __syncthreads();
    int off = wsum[0] + wsum[1] + wsum[2] + wsum[3];
    int i = blockIdx.x * 256 + t;
    if (i < N_NODES) {
        int r = row_ptr[i] + off;
        row_ptr[i] = r;
        cursor[i] = r;
    }
    if (i == 0) row_ptr[N_NODES] = N_EDGES;
}

// ---------------------------------------------------------------------------
// CSR fill: 4 edges/thread -> 4 independent outstanding atomics per lane
// (concurrency x4 vs R11; fill was atomic-concurrency-bound). ushort payload.
// ---------------------------------------------------------------------------
__global__ __launch_bounds__(256) void fill_kernel(const int* __restrict__ src,
                                                   const int* __restrict__ dst,
                                                   int* __restrict__ cursor,
                                                   unsigned short* __restrict__ csr16) {
    int tid = blockIdx.x * 256 + threadIdx.x;
    int e3 = tid + 3 * EDGE_T;
    bool v3 = e3 < N_EDGES;
    int d0 = dst[tid];
    int d1 = dst[tid + EDGE_T];
    int d2 = dst[tid + 2 * EDGE_T];
    int d3 = dst[v3 ? e3 : 0];
    int s0 = src[tid];
    int s1 = src[tid + EDGE_T];
    int s2 = src[tid + 2 * EDGE_T];
    int s3 = src[v3 ? e3 : 0];
    int p0 = atomicAdd(&cursor[d0], 1);
    int p1 = atomicAdd(&cursor[d1], 1);
    int p2 = atomicAdd(&cursor[d2], 1);
    int p3 = v3 ? atomicAdd(&cursor[d3], 1) : 0;
    csr16[p0] = (unsigned short)s0;
    csr16[p1] = (unsigned short)s1;
    csr16[p2] = (unsigned short)s2;
    if (v3) csr16[p3] = (unsigned short)s3;
}

// ---------------------------------------------------------------------------
// Prep:
//   i < 16384   : WfA fragment-major bf16 W1 (f = phase*32 + kc*8 + nt)
//   i < 21504   : WfB fragment-major bf16 W2 (f = kc*5 + nt), n<40 W2l else W2r
//   else        : pack x row-major -> bf16 (uint4 per 8 floats)
// ---------------------------------------------------------------------------
__global__ __launch_bounds__(256) void prep_kernel(
    const float* __restrict__ W1l, const float* __restrict__ W1r,
    const float* __restrict__ W2l, const float* __restrict__ W2r,
    const float* __restrict__ x, unsigned* __restrict__ WfA,
    unsigned* __restrict__ WfB, unsigned* __restrict__ x_bf16) {
    int i = blockIdx.x * 256 + threadIdx.x;
    if (i < 16384) {
        int f = i >> 8, r = i & 255;
        int lane = r >> 2, u = r & 3;
        int phase = f >> 5, kc = (f >> 3) & 3, nt = f & 7;
        int k0 = phase * 128 + kc * 32 + (lane >> 4) * 8 + u * 2;
        int n = nt * 16 + (lane & 15);
        float w0, w1;
        if (k0 < 128) {
            w0 = W1l[n * 128 + k0];
            w1 = W1l[n * 128 + k0 + 1];
        } else {
            w0 = W1r[n * 128 + k0 - 128];
            w1 = W1r[n * 128 + k0 - 127];
        }
        WfA[i] = bfpack(w0, w1);
    } else if (i < 21504) {
        int j = i - 16384;
        int f = j >> 8, r = j & 255;
        int lane = r >> 2, u = r & 3;
        int kc = f / 5, nt = f % 5;
        int k0 = kc * 32 + (lane >> 4) * 8 + u * 2;
        int n = nt * 16 + (lane & 15);
        float w0, w1;
        if (n < 40) {
            w0 = W2l[n * 128 + k0];
            w1 = W2l[n * 128 + k0 + 1];
        } else {
            w0 = W2r[(n - 40) * 128 + k0];
            w1 = W2r[(n - 40) * 128 + k0 + 1];
        }
        WfB[j] = bfpack(w0, w1);
    } else {
        int j = i - 21504;
        if (j < 800000) {
            const float4* xf = (const float4*)x;
            float4 a = xf[(size_t)j * 2];
            float4 b = xf[(size_t)j * 2 + 1];
            uint4 o;
            o.x = bfpack(a.x, a.y);
            o.y = bfpack(a.z, a.w);
            o.z = bfpack(b.x, b.y);
            o.w = bfpack(b.z, b.w);
            ((uint4*)x_bf16)[j] = o;
        }
    }
}

// ---------------------------------------------------------------------------
// Gather-mean layer 1 (bf16 x): subgroup-per-node, shuffle-free.
// 16 lanes own a node; 4 edges in flight; fp32 accumulate; emits bf16 agg1.
// ---------------------------------------------------------------------------
__global__ __launch_bounds__(256) void gather1_kernel(const unsigned short* __restrict__ csr16,
                                                      const int* __restrict__ row_ptr,
                                                      const unsigned* __restrict__ x_bf16,
                                                      unsigned* __restrict__ agg1b) {
    int sg = threadIdx.x >> 4;
    int li = threadIdx.x & 15;
    int gid = blockIdx.x * 16 + sg;
    if (gid >= N_NODES) return;
    int beg = row_ptr[gid], end = row_ptr[gid + 1];
    int n = end - beg;
    const uint4* xb = (const uint4*)x_bf16;
    float acc[8];
#pragma unroll
    for (int j = 0; j < 8; ++j) acc[j] = 0.f;

    int e = beg;
    for (; e + 3 < end; e += 4) {
        int s0 = csr16[e], s1 = csr16[e + 1];
        int s2 = csr16[e + 2], s3 = csr16[e + 3];
        uint4 t0 = xb[(size_t)s0 * 16 + li];
        uint4 t1 = xb[(size_t)s1 * 16 + li];
        uint4 t2 = xb[(size_t)s2 * 16 + li];
        uint4 t3 = xb[(size_t)s3 * 16 + li];
        acc[0] += bflo(t0.x) + bflo(t1.x) + bflo(t2.x) + bflo(t3.x);
        acc[1] += bfhi(t0.x) + bfhi(t1.x) + bfhi(t2.x) + bfhi(t3.x);
        acc[2] += bflo(t0.y) + bflo(t1.y) + bflo(t2.y) + bflo(t3.y);
        acc[3] += bfhi(t0.y) + bfhi(t1.y) + bfhi(t2.y) + bfhi(t3.y);
        acc[4] += bflo(t0.z) + bflo(t1.z) + bflo(t2.z) + bflo(t3.z);
        acc[5] += bfhi(t0.z) + bfhi(t1.z) + bfhi(t2.z) + bfhi(t3.z);
        acc[6] += bflo(t0.w) + bflo(t1.w) + bflo(t2.w) + bflo(t3.w);
        acc[7] += bfhi(t0.w) + bfhi(t1.w) + bfhi(t2.w) + bfhi(t3.w);
    }
    for (; e < end; ++e) {
        int s = csr16[e];
        uint4 t0 = xb[(size_t)s * 16 + li];
        acc[0] += bflo(t0.x); acc[1] += bfhi(t0.x);
        acc[2] += bflo(t0.y); acc[3] += bfhi(t0.y);
        acc[4] += bflo(t0.z); acc[5] += bfhi(t0.z);
        acc[6] += bflo(t0.w); acc[7] += bfhi(t0.w);
    }
    float inv = 1.0f / fmaxf((float)n, 1.0f);
    uint4 o;
    o.x = bfpack(acc[0] * inv, acc[1] * inv);
    o.y = bfpack(acc[2] * inv, acc[3] * inv);
    o.z = bfpack(acc[4] * inv, acc[5] * inv);
    o.w = bfpack(acc[6] * inv, acc[7] * inv);
    ((uint4*)agg1b)[(size_t)gid * 16 + li] = o;
}

// ---------------------------------------------------------------------------
// GEMM1 via MFMA (bf16): h = BN(ReLU(agg1 @ W1l^T + b1 + x @ W1r^T))
// 64 rows x 128 cols; 4 waves x 16-row strip x 8 n-tiles; A staged in LDS;
// B frags fragment-major global (L2-hot). Emits h as bf16.
// ---------------------------------------------------------------------------
__global__ __launch_bounds__(256) void gemm1_kernel(
    const unsigned* __restrict__ agg1b, const unsigned* __restrict__ xb,
    const unsigned* __restrict__ WfA, const float* __restrict__ b1,
    const float* __restrict__ gamma, const float* __restrict__ beta,
    const float* __restrict__ rmean, const float* __restrict__ rvar,
    unsigned short* __restrict__ hb) {
    __shared__ unsigned Asu[64 * 68];
    const int t = threadIdx.x;
    const int wid = __builtin_amdgcn_readfirstlane(t >> 6);
    const int lane = t & 63;
    const int li = lane & 15;
    const int quad = lane >> 4;
    const int mbase = blockIdx.x * 64;

    f32x4 dacc[8];
#pragma unroll
    for (int nt = 0; nt < 8; ++nt) dacc[nt] = (f32x4){0.f, 0.f, 0.f, 0.f};

    for (int phase = 0; phase < 2; ++phase) {
        const unsigned* __restrict__ A = phase ? xb : agg1b;
        __syncthreads();
#pragma unroll
        for (int i = 0; i < 4; ++i) {
            int e = i * 256 + t;
            int row = e >> 4, seg = e & 15;
            int rr = mbase + row;
            rr = (rr < N_NODES) ? rr : N_NODES - 1;
            uint4 v = ((const uint4*)A)[(size_t)rr * 16 + seg];
            *(uint4*)&Asu[row * 68 + seg * 4] = v;
        }
        __syncthreads();
        bf16x8 af[4];
#pragma unroll
        for (int kc = 0; kc < 4; ++kc)
            af[kc] = *(const bf16x8*)&Asu[(wid * 16 + li) * 68 + kc * 16 + quad * 4];

        const unsigned* __restrict__ Wp = WfA + phase * 8192;
#pragma unroll
        for (int nt = 0; nt < 8; ++nt) {
#pragma unroll
            for (int kc = 0; kc < 4; ++kc) {
                bf16x8 bfr = *(const bf16x8*)(Wp + (size_t)(kc * 8 + nt) * 256 + lane * 4);
                dacc[nt] = __builtin_amdgcn_mfma_f32_16x16x32_bf16(af[kc], bfr, dacc[nt], 0, 0, 0);
            }
        }
    }

#pragma unroll
    for (int nt = 0; nt < 8; ++nt) {
        int cg = nt * 16 + li;
        float sc = gamma[cg] * rsqrtf(rvar[cg] + BN_EPS);
        float sh = fmaf(-rmean[cg], sc, beta[cg]);
        float bb = b1[cg];
#pragma unroll
        for (int r = 0; r < 4; ++r) {
            int row = mbase + wid * 16 + quad * 4 + r;
            if (row < N_NODES) {
                float pre = dacc[nt][r] + bb;
                hb[(size_t)row * 128 + cg] = bfr1(fmaf(fmaxf(pre, 0.f), sc, sh));
            }
        }
    }
}

// ---------------------------------------------------------------------------
// GEMM2 via MFMA (bf16): [z2 | p2] = h @ [W2l^T | W2r^T]  (80 cols, 5 n-tiles)
// z2 bf16 (stride 40 ushorts), p2 fp32 (stride 40).
// ---------------------------------------------------------------------------
__global__ __launch_bounds__(256) void gemm2_kernel(const unsigned short* __restrict__ hb,
                                                    const unsigned* __restrict__ WfB,
                                                    unsigned short* __restrict__ z2s,
                                                    float* __restrict__ p2) {
    __shared__ unsigned Asu[64 * 68];
    const int t = threadIdx.x;
    const int wid = __builtin_amdgcn_readfirstlane(t >> 6);
    const int lane = t & 63;
    const int li = lane & 15;
    const int quad = lane >> 4;
    const int mbase = blockIdx.x * 64;

    f32x4 dacc[5];
#pragma unroll
    for (int nt = 0; nt < 5; ++nt) dacc[nt] = (f32x4){0.f, 0.f, 0.f, 0.f};

#pragma unroll
    for (int i = 0; i < 4; ++i) {
        int e = i * 256 + t;
        int row = e >> 4, seg = e & 15;
        int rr = mbase + row;
        rr = (rr < N_NODES) ? rr : N_NODES - 1;
        uint4 v = ((const uint4*)hb)[(size_t)rr * 16 + seg];
        *(uint4*)&Asu[row * 68 + seg * 4] = v;
    }
    __syncthreads();
    bf16x8 af[4];
#pragma unroll
    for (int kc = 0; kc < 4; ++kc)
        af[kc] = *(const bf16x8*)&Asu[(wid * 16 + li) * 68 + kc * 16 + quad * 4];

#pragma unroll
    for (int nt = 0; nt < 5; ++nt) {
#pragma unroll
        for (int kc = 0; kc < 4; ++kc) {
            bf16x8 bfr = *(const bf16x8*)(WfB + (size_t)(kc * 5 + nt) * 256 + lane * 4);
            dacc[nt] = __builtin_amdgcn_mfma_f32_16x16x32_bf16(af[kc], bfr, dacc[nt], 0, 0, 0);
        }
    }

#pragma unroll
    for (int nt = 0; nt < 5; ++nt) {
        int cg = nt * 16 + li;
#pragma unroll
        for (int r = 0; r < 4; ++r) {
            int row = mbase + wid * 16 + quad * 4 + r;
            if (row < N_NODES) {
                float v = dacc[nt][r];
                if (cg < 40) z2s[(size_t)row * 40 + cg] = bfr1(v);
                else p2[(size_t)row * 40 + (cg - 40)] = v;
            }
        }
    }
}

// ---------------------------------------------------------------------------
// Gather layer 2 + final (bf16 z2): subgroup-per-node, shuffle-free.
// 10 lanes own a node; 25 subgroups/block; 4 edges in flight.
// ---------------------------------------------------------------------------
__global__ __launch_bounds__(256) void gather2_kernel(const unsigned short* __restrict__ csr16,
                                                      const int* __restrict__ row_ptr,
                                                      const unsigned short* __restrict__ z2s,
                                                      const float* __restrict__ p2,
                                                      const float* __restrict__ b2,
                                                      float* __restrict__ out) {
    int t = threadIdx.x;
    int sub = t / 10;
    int li = t - sub * 10;
    if (sub >= 25) return;
    int gid = blockIdx.x * 25 + sub;
    if (gid >= N_NODES) return;
    int beg = row_ptr[gid], end = row_ptr[gid + 1];
    int n = end - beg;
    const uint2* z2 = (const uint2*)z2s;
    float4 acc = {0.f, 0.f, 0.f, 0.f};
    int e = beg;
    for (; e + 3 < end; e += 4) {
        int s0 = csr16[e], s1 = csr16[e + 1];
        int s2 = csr16[e + 2], s3 = csr16[e + 3];
        uint2 t0 = z2[(size_t)s0 * 10 + li];
        uint2 t1 = z2[(size_t)s1 * 10 + li];
        uint2 t2 = z2[(size_t)s2 * 10 + li];
        uint2 t3 = z2[(size_t)s3 * 10 + li];
        acc.x += bflo(t0.x) + bflo(t1.x) + bflo(t2.x) + bflo(t3.x);
        acc.y += bfhi(t0.x) + bfhi(t1.x) + bfhi(t2.x) + bfhi(t3.x);
        acc.z += bflo(t0.y) + bflo(t1.y) + bflo(t2.y) + bflo(t3.y);
        acc.w += bfhi(t0.y) + bfhi(t1.y) + bfhi(t2.y) + bfhi(t3.y);
    }
    for (; e < end; ++e) {
        int s = csr16[e];
        uint2 t0 = z2[(size_t)s * 10 + li];
        acc.x += bflo(t0.x); acc.y += bfhi(t0.x);
        acc.z += bflo(t0.y); acc.w += bfhi(t0.y);
    }
    float inv = 1.0f / fmaxf((float)n, 1.0f);
    float4 p = ((const float4*)p2)[(size_t)gid * 10 + li];
    float4 bb = ((const float4*)b2)[li];
    float4 r;
    r.x = fmaf(acc.x, inv, p.x + bb.x);
    r.y = fmaf(acc.y, inv, p.y + bb.y);
    r.z = fmaf(acc.z, inv, p.z + bb.z);
    r.w = fmaf(acc.w, inv, p.w + bb.w);
    ((float4*)out)[(size_t)gid * 10 + li] = r;
}

// ---------------------------------------------------------------------------
// Launch. ws layout (int units):
//   deg_i[50048] (memset 0), cursor[50048] (seeded by scanC),
//   row_ptr[50052], blk_sum[256]
//   csr16  ushort[800000] (= 400000 ints)
//   WfA u32[16384], WfB u32[5120]
//   x_bf16 u32[3200000]
//   agg1b u32[50048*64]  -- z2s ushort[50048*40] + p2 f32[50048*40] alias it
//   hb ushort[50048*128]
// ---------------------------------------------------------------------------
extern "C" void kernel_launch(void* const* d_in, const int* in_sizes, int n_in,
                              void* d_out, int out_size, void* d_ws, size_t ws_size,
                              hipStream_t stream) {
    const float* x     = (const float*)d_in[0];
    const int*   ei    = (const int*)d_in[1];
    const float* W1l   = (const float*)d_in[2];
    const float* b1    = (const float*)d_in[3];
    const float* W1r   = (const float*)d_in[4];
    const float* gamma = (const float*)d_in[5];
    const float* beta  = (const float*)d_in[6];
    const float* rmean = (const float*)d_in[7];
    const float* rvar  = (const float*)d_in[8];
    const float* W2l   = (const float*)d_in[9];
    const float* b2    = (const float*)d_in[10];
    const float* W2r   = (const float*)d_in[11];
    float* out = (float*)d_out;

    int* deg_i            = (int*)d_ws;
    int* cursor           = deg_i + 50048;
    int* row_ptr          = cursor + 50048;
    int* blk_sum          = row_ptr + 50052;
    unsigned short* csr16 = (unsigned short*)(blk_sum + 256);
    unsigned* WfA         = (unsigned*)((int*)(blk_sum + 256) + 400000);
    unsigned* WfB         = WfA + 16384;
    unsigned* x_bf16      = WfB + 5120;
    unsigned* agg1b       = x_bf16 + 3200000;
    unsigned short* z2s   = (unsigned short*)agg1b;     // alias (agg1b dead after gemm1)
    float* p2             = (float*)(agg1b + 50048 * 20);
    unsigned short* hb    = (unsigned short*)(agg1b + (size_t)50048 * 64);

    const int* src = ei;
    const int* dst = ei + N_EDGES;

    hipMemsetAsync(deg_i, 0, (size_t)50048 * sizeof(int), stream);

    deg_kernel<<<EDGE_T / 256, 256, 0, stream>>>(dst, deg_i);
    scanA_kernel<<<SCAN_BLOCKS, 256, 0, stream>>>(deg_i, row_ptr, blk_sum);
    scanC_kernel<<<SCAN_BLOCKS, 256, 0, stream>>>(row_ptr, cursor, blk_sum);
    fill_kernel<<<EDGE_T / 256, 256, 0, stream>>>(src, dst, cursor, csr16);

    prep_kernel<<<(21504 + 800000 + 255) / 256, 256, 0, stream>>>(W1l, W1r, W2l, W2r,
                                                                  x, WfA, WfB, x_bf16);

    gather1_kernel<<<(N_NODES + 15) / 16, 256, 0, stream>>>(csr16, row_ptr, x_bf16, agg1b);

    gemm1_kernel<<<(N_NODES + 63) / 64, 256, 0, stream>>>(agg1b, x_bf16, WfA, b1, gamma,
                                                          beta, rmean, rvar, hb);

    gemm2_kernel<<<(N_NODES + 63) / 64, 256, 0, stream>>>(hb, WfB, z2s, p2);

    gather2_kernel<<<(N_NODES + 24) / 25, 256, 0, stream>>>(csr16, row_ptr, z2s, p2, b2, out);
}

// Round 13
// 255.174 us; speedup vs baseline: 2.2492x; 1.0104x over previous
//
#include <hip/hip_runtime.h>

#define N_NODES 50000
#define N_EDGES 800000
#define N_FEAT 128
#define N_HID 128
#define N_CLS 40
#define BN_EPS 1e-5f

#define SCAN_BLOCKS ((N_NODES + 255) / 256)  // 196
#define EDGE_T 200192                        // 782 blocks * 256 (4 edges/thread)
#define DEG_BLOCKS 782
#define PREP_BLOCKS 3209                     // ceil((21504+800000)/256)

typedef short bf16x8 __attribute__((ext_vector_type(8)));
typedef float f32x4 __attribute__((ext_vector_type(4)));

// RNE float->bf16 helpers
__device__ __forceinline__ unsigned bfpack(float a, float b) {
    unsigned ua = __float_as_uint(a), ub = __float_as_uint(b);
    ua = (ua + 0x7FFFu + ((ua >> 16) & 1u)) >> 16;
    ub = (ub + 0x7FFFu + ((ub >> 16) & 1u)) >> 16;
    return ua | (ub << 16);
}
__device__ __forceinline__ unsigned short bfr1(float a) {
    unsigned u = __float_as_uint(a);
    u = (u + 0x7FFFu + ((u >> 16) & 1u)) >> 16;
    return (unsigned short)u;
}
__device__ __forceinline__ float bflo(unsigned u) { return __uint_as_float(u << 16); }
__device__ __forceinline__ float bfhi(unsigned u) { return __uint_as_float(u & 0xFFFF0000u); }

// ---------------------------------------------------------------------------
// Fused deg + prep: blocks [0,782) do the degree histogram (4 edges/thread,
// fire-and-forget atomics); blocks [782,3991) transpose/pack weights and x.
// Latency-bound atomics overlap with BW-bound packing in one dispatch.
// ---------------------------------------------------------------------------
__global__ __launch_bounds__(256) void degprep_kernel(
    const int* __restrict__ dst, int* __restrict__ deg_i,
    const float* __restrict__ W1l, const float* __restrict__ W1r,
    const float* __restrict__ W2l, const float* __restrict__ W2r,
    const float* __restrict__ x, unsigned* __restrict__ WfA,
    unsigned* __restrict__ WfB, unsigned* __restrict__ x_bf16) {
    int b = blockIdx.x;
    if (b < DEG_BLOCKS) {
        int tid = b * 256 + threadIdx.x;
        int d0 = dst[tid];
        int d1 = dst[tid + EDGE_T];
        int d2 = dst[tid + 2 * EDGE_T];
        int e3 = tid + 3 * EDGE_T;
        atomicAdd(&deg_i[d0], 1);
        atomicAdd(&deg_i[d1], 1);
        atomicAdd(&deg_i[d2], 1);
        if (e3 < N_EDGES) atomicAdd(&deg_i[dst[e3]], 1);
        return;
    }
    int i = (b - DEG_BLOCKS) * 256 + threadIdx.x;
    if (i < 16384) {
        int f = i >> 8, r = i & 255;
        int lane = r >> 2, u = r & 3;
        int phase = f >> 5, kc = (f >> 3) & 3, nt = f & 7;
        int k0 = phase * 128 + kc * 32 + (lane >> 4) * 8 + u * 2;
        int n = nt * 16 + (lane & 15);
        float w0, w1;
        if (k0 < 128) {
            w0 = W1l[n * 128 + k0];
            w1 = W1l[n * 128 + k0 + 1];
        } else {
            w0 = W1r[n * 128 + k0 - 128];
            w1 = W1r[n * 128 + k0 - 127];
        }
        WfA[i] = bfpack(w0, w1);
    } else if (i < 21504) {
        int j = i - 16384;
        int f = j >> 8, r = j & 255;
        int lane = r >> 2, u = r & 3;
        int kc = f / 5, nt = f % 5;
        int k0 = kc * 32 + (lane >> 4) * 8 + u * 2;
        int n = nt * 16 + (lane & 15);
        float w0, w1;
        if (n < 40) {
            w0 = W2l[n * 128 + k0];
            w1 = W2l[n * 128 + k0 + 1];
        } else {
            w0 = W2r[(n - 40) * 128 + k0];
            w1 = W2r[(n - 40) * 128 + k0 + 1];
        }
        WfB[j] = bfpack(w0, w1);
    } else {
        int j = i - 21504;
        if (j < 800000) {
            const float4* xf = (const float4*)x;
            float4 a = xf[(size_t)j * 2];
            float4 bq = xf[(size_t)j * 2 + 1];
            uint4 o;
            o.x = bfpack(a.x, a.y);
            o.y = bfpack(a.z, a.w);
            o.z = bfpack(bq.x, bq.y);
            o.w = bfpack(bq.z, bq.w);
            ((uint4*)x_bf16)[j] = o;
        }
    }
}

// ---------------------------------------------------------------------------
// scanA: per-block exclusive scan of degrees; block totals out.
// ---------------------------------------------------------------------------
__global__ __launch_bounds__(256) void scanA_kernel(const int* __restrict__ deg_i,
                                                    int* __restrict__ row_ptr,
                                                    int* __restrict__ blk_sum) {
    __shared__ int tmp[256];
    int t = threadIdx.x;
    int i = blockIdx.x * 256 + t;
    int v = (i < N_NODES) ? deg_i[i] : 0;
    tmp[t] = v;
    __syncthreads();
    for (int off = 1; off < 256; off <<= 1) {
        int a = (t >= off) ? tmp[t - off] : 0;
        __syncthreads();
        if (t >= off) tmp[t] += a;
        __syncthreads();
    }
    if (i < N_NODES) row_ptr[i] = tmp[t] - v;
    if (t == 255) blk_sum[blockIdx.x] = tmp[255];
}

// ---------------------------------------------------------------------------
// scanC (fused scanB): each block reduces blk_sum[0..bid-1] itself,
// applies the offset, seeds cursor with absolute start positions.
// ---------------------------------------------------------------------------
__global__ __launch_bounds__(256) void scanC_kernel(int* __restrict__ row_ptr,
                                                    int* __restrict__ cursor,
                                                    const int* __restrict__ blk_sum) {
    __shared__ int wsum[4];
    int t = threadIdx.x;
    int v = (t < blockIdx.x && t < SCAN_BLOCKS) ? blk_sum[t] : 0;
    int s = v;
#pragma unroll
    for (int o = 32; o > 0; o >>= 1) s += __shfl_down(s, o);
    if ((t & 63) == 0) wsum[t >> 6] = s;
    __syncthreads();
    int off = wsum[0] + wsum[1] + wsum[2] + wsum[3];
    int i = blockIdx.x * 256 + t;
    if (i < N_NODES) {
        int r = row_ptr[i] + off;
        row_ptr[i] = r;
        cursor[i] = r;
    }
    if (i == 0) row_ptr[N_NODES] = N_EDGES;
}

// ---------------------------------------------------------------------------
// CSR fill: 4 edges/thread -> 4 outstanding atomics per lane. ushort payload.
// ---------------------------------------------------------------------------
__global__ __launch_bounds__(256) void fill_kernel(const int* __restrict__ src,
                                                   const int* __restrict__ dst,
                                                   int* __restrict__ cursor,
                                                   unsigned short* __restrict__ csr16) {
    int tid = blockIdx.x * 256 + threadIdx.x;
    int e3 = tid + 3 * EDGE_T;
    bool v3 = e3 < N_EDGES;
    int d0 = dst[tid];
    int d1 = dst[tid + EDGE_T];
    int d2 = dst[tid + 2 * EDGE_T];
    int d3 = dst[v3 ? e3 : 0];
    int s0 = src[tid];
    int s1 = src[tid + EDGE_T];
    int s2 = src[tid + 2 * EDGE_T];
    int s3 = src[v3 ? e3 : 0];
    int p0 = atomicAdd(&cursor[d0], 1);
    int p1 = atomicAdd(&cursor[d1], 1);
    int p2 = atomicAdd(&cursor[d2], 1);
    int p3 = v3 ? atomicAdd(&cursor[d3], 1) : 0;
    csr16[p0] = (unsigned short)s0;
    csr16[p1] = (unsigned short)s1;
    csr16[p2] = (unsigned short)s2;
    if (v3) csr16[p3] = (unsigned short)s3;
}

// ---------------------------------------------------------------------------
// Gather-mean layer 1 (bf16 x): subgroup-per-node, shuffle-free, ILP-8.
// 16 lanes own a node; 8 edges in flight; fp32 accumulate; emits bf16 agg1.
// ---------------------------------------------------------------------------
__global__ __launch_bounds__(256) void gather1_kernel(const unsigned short* __restrict__ csr16,
                                                      const int* __restrict__ row_ptr,
                                                      const unsigned* __restrict__ x_bf16,
                                                      unsigned* __restrict__ agg1b) {
    int sg = threadIdx.x >> 4;
    int li = threadIdx.x & 15;
    int gid = blockIdx.x * 16 + sg;
    if (gid >= N_NODES) return;
    int beg = row_ptr[gid], end = row_ptr[gid + 1];
    int n = end - beg;
    const uint4* xb = (const uint4*)x_bf16;
    float acc[8];
#pragma unroll
    for (int j = 0; j < 8; ++j) acc[j] = 0.f;

    int e = beg;
    for (; e + 7 < end; e += 8) {
        uint4 tv[8];
#pragma unroll
        for (int q = 0; q < 8; ++q) {
            int s = csr16[e + q];
            tv[q] = xb[(size_t)s * 16 + li];
        }
#pragma unroll
        for (int q = 0; q < 8; ++q) {
            acc[0] += bflo(tv[q].x); acc[1] += bfhi(tv[q].x);
            acc[2] += bflo(tv[q].y); acc[3] += bfhi(tv[q].y);
            acc[4] += bflo(tv[q].z); acc[5] += bfhi(tv[q].z);
            acc[6] += bflo(tv[q].w); acc[7] += bfhi(tv[q].w);
        }
    }
    if (e + 3 < end) {
        uint4 tv[4];
#pragma unroll
        for (int q = 0; q < 4; ++q) {
            int s = csr16[e + q];
            tv[q] = xb[(size_t)s * 16 + li];
        }
#pragma unroll
        for (int q = 0; q < 4; ++q) {
            acc[0] += bflo(tv[q].x); acc[1] += bfhi(tv[q].x);
            acc[2] += bflo(tv[q].y); acc[3] += bfhi(tv[q].y);
            acc[4] += bflo(tv[q].z); acc[5] += bfhi(tv[q].z);
            acc[6] += bflo(tv[q].w); acc[7] += bfhi(tv[q].w);
        }
        e += 4;
    }
    for (; e < end; ++e) {
        int s = csr16[e];
        uint4 t0 = xb[(size_t)s * 16 + li];
        acc[0] += bflo(t0.x); acc[1] += bfhi(t0.x);
        acc[2] += bflo(t0.y); acc[3] += bfhi(t0.y);
        acc[4] += bflo(t0.z); acc[5] += bfhi(t0.z);
        acc[6] += bflo(t0.w); acc[7] += bfhi(t0.w);
    }
    float inv = 1.0f / fmaxf((float)n, 1.0f);
    uint4 o;
    o.x = bfpack(acc[0] * inv, acc[1] * inv);
    o.y = bfpack(acc[2] * inv, acc[3] * inv);
    o.z = bfpack(acc[4] * inv, acc[5] * inv);
    o.w = bfpack(acc[6] * inv, acc[7] * inv);
    ((uint4*)agg1b)[(size_t)gid * 16 + li] = o;
}

// ---------------------------------------------------------------------------
// GEMM1 via MFMA (bf16): h = BN(ReLU(agg1 @ W1l^T + b1 + x @ W1r^T))
// 64 rows x 128 cols; 4 waves x 16-row strip x 8 n-tiles; A staged in LDS;
// B frags fragment-major global (L2-hot). Emits h as bf16.
// ---------------------------------------------------------------------------
__global__ __launch_bounds__(256) void gemm1_kernel(
    const unsigned* __restrict__ agg1b, const unsigned* __restrict__ xb,
    const unsigned* __restrict__ WfA, const float* __restrict__ b1,
    const float* __restrict__ gamma, const float* __restrict__ beta,
    const float* __restrict__ rmean, const float* __restrict__ rvar,
    unsigned short* __restrict__ hb) {
    __shared__ unsigned Asu[64 * 68];
    const int t = threadIdx.x;
    const int wid = __builtin_amdgcn_readfirstlane(t >> 6);
    const int lane = t & 63;
    const int li = lane & 15;
    const int quad = lane >> 4;
    const int mbase = blockIdx.x * 64;

    f32x4 dacc[8];
#pragma unroll
    for (int nt = 0; nt < 8; ++nt) dacc[nt] = (f32x4){0.f, 0.f, 0.f, 0.f};

    for (int phase = 0; phase < 2; ++phase) {
        const unsigned* __restrict__ A = phase ? xb : agg1b;
        __syncthreads();
#pragma unroll
        for (int i = 0; i < 4; ++i) {
            int e = i * 256 + t;
            int row = e >> 4, seg = e & 15;
            int rr = mbase + row;
            rr = (rr < N_NODES) ? rr : N_NODES - 1;
            uint4 v = ((const uint4*)A)[(size_t)rr * 16 + seg];
            *(uint4*)&Asu[row * 68 + seg * 4] = v;
        }
        __syncthreads();
        bf16x8 af[4];
#pragma unroll
        for (int kc = 0; kc < 4; ++kc)
            af[kc] = *(const bf16x8*)&Asu[(wid * 16 + li) * 68 + kc * 16 + quad * 4];

        const unsigned* __restrict__ Wp = WfA + phase * 8192;
#pragma unroll
        for (int nt = 0; nt < 8; ++nt) {
#pragma unroll
            for (int kc = 0; kc < 4; ++kc) {
                bf16x8 bfr = *(const bf16x8*)(Wp + (size_t)(kc * 8 + nt) * 256 + lane * 4);
                dacc[nt] = __builtin_amdgcn_mfma_f32_16x16x32_bf16(af[kc], bfr, dacc[nt], 0, 0, 0);
            }
        }
    }

#pragma unroll
    for (int nt = 0; nt < 8; ++nt) {
        int cg = nt * 16 + li;
        float sc = gamma[cg] * rsqrtf(rvar[cg] + BN_EPS);
        float sh = fmaf(-rmean[cg], sc, beta[cg]);
        float bb = b1[cg];
#pragma unroll
        for (int r = 0; r < 4; ++r) {
            int row = mbase + wid * 16 + quad * 4 + r;
            if (row < N_NODES) {
                float pre = dacc[nt][r] + bb;
                hb[(size_t)row * 128 + cg] = bfr1(fmaf(fmaxf(pre, 0.f), sc, sh));
            }
        }
    }
}

// ---------------------------------------------------------------------------
// GEMM2 via MFMA (bf16): [z2 | p2] = h @ [W2l^T | W2r^T]  (80 cols, 5 n-tiles)
// z2 bf16 (stride 40 ushorts), p2 fp32 (stride 40).
// ---------------------------------------------------------------------------
__global__ __launch_bounds__(256) void gemm2_kernel(const unsigned short* __restrict__ hb,
                                                    const unsigned* __restrict__ WfB,
                                                    unsigned short* __restrict__ z2s,
                                                    float* __restrict__ p2) {
    __shared__ unsigned Asu[64 * 68];
    const int t = threadIdx.x;
    const int wid = __builtin_amdgcn_readfirstlane(t >> 6);
    const int lane = t & 63;
    const int li = lane & 15;
    const int quad = lane >> 4;
    const int mbase = blockIdx.x * 64;

    f32x4 dacc[5];
#pragma unroll
    for (int nt = 0; nt < 5; ++nt) dacc[nt] = (f32x4){0.f, 0.f, 0.f, 0.f};

#pragma unroll
    for (int i = 0; i < 4; ++i) {
        int e = i * 256 + t;
        int row = e >> 4, seg = e & 15;
        int rr = mbase + row;
        rr = (rr < N_NODES) ? rr : N_NODES - 1;
        uint4 v = ((const uint4*)hb)[(size_t)rr * 16 + seg];
        *(uint4*)&Asu[row * 68 + seg * 4] = v;
    }
    __syncthreads();
    bf16x8 af[4];
#pragma unroll
    for (int kc = 0; kc < 4; ++kc)
        af[kc] = *(const bf16x8*)&Asu[(wid * 16 + li) * 68 + kc * 16 + quad * 4];

#pragma unroll
    for (int nt = 0; nt < 5; ++nt) {
#pragma unroll
        for (int kc = 0; kc < 4; ++kc) {
            bf16x8 bfr = *(const bf16x8*)(WfB + (size_t)(kc * 5 + nt) * 256 + lane * 4);
            dacc[nt] = __builtin_amdgcn_mfma_f32_16x16x32_bf16(af[kc], bfr, dacc[nt], 0, 0, 0);
        }
    }

#pragma unroll
    for (int nt = 0; nt < 5; ++nt) {
        int cg = nt * 16 + li;
#pragma unroll
        for (int r = 0; r < 4; ++r) {
            int row = mbase + wid * 16 + quad * 4 + r;
            if (row < N_NODES) {
                float v = dacc[nt][r];
                if (cg < 40) z2s[(size_t)row * 40 + cg] = bfr1(v);
                else p2[(size_t)row * 40 + (cg - 40)] = v;
            }
        }
    }
}

// ---------------------------------------------------------------------------
// Gather layer 2 + final (bf16 z2): subgroup-per-node, shuffle-free, ILP-8.
// 10 lanes own a node; 25 subgroups/block; 8 edges in flight.
// ---------------------------------------------------------------------------
__global__ __launch_bounds__(256) void gather2_kernel(const unsigned short* __restrict__ csr16,
                                                      const int* __restrict__ row_ptr,
                                                      const unsigned short* __restrict__ z2s,
                                                      const float* __restrict__ p2,
                                                      const float* __restrict__ b2,
                                                      float* __restrict__ out) {
    int t = threadIdx.x;
    int sub = t / 10;
    int li = t - sub * 10;
    if (sub >= 25) return;
    int gid = blockIdx.x * 25 + sub;
    if (gid >= N_NODES) return;
    int beg = row_ptr[gid], end = row_ptr[gid + 1];
    int n = end - beg;
    const uint2* z2 = (const uint2*)z2s;
    float4 acc = {0.f, 0.f, 0.f, 0.f};
    int e = beg;
    for (; e + 7 < end; e += 8) {
        uint2 tv[8];
#pragma unroll
        for (int q = 0; q < 8; ++q) {
            int s = csr16[e + q];
            tv[q] = z2[(size_t)s * 10 + li];
        }
#pragma unroll
        for (int q = 0; q < 8; ++q) {
            acc.x += bflo(tv[q].x); acc.y += bfhi(tv[q].x);
            acc.z += bflo(tv[q].y); acc.w += bfhi(tv[q].y);
        }
    }
    if (e + 3 < end) {
        uint2 tv[4];
#pragma unroll
        for (int q = 0; q < 4; ++q) {
            int s = csr16[e + q];
            tv[q] = z2[(size_t)s * 10 + li];
        }
#pragma unroll
        for (int q = 0; q < 4; ++q) {
            acc.x += bflo(tv[q].x); acc.y += bfhi(tv[q].x);
            acc.z += bflo(tv[q].y); acc.w += bfhi(tv[q].y);
        }
        e += 4;
    }
    for (; e < end; ++e) {
        int s = csr16[e];
        uint2 t0 = z2[(size_t)s * 10 + li];
        acc.x += bflo(t0.x); acc.y += bfhi(t0.x);
        acc.z += bflo(t0.y); acc.w += bfhi(t0.y);
    }
    float inv = 1.0f / fmaxf((float)n, 1.0f);
    float4 p = ((const float4*)p2)[(size_t)gid * 10 + li];
    float4 bb = ((const float4*)b2)[li];
    float4 r;
    r.x = fmaf(acc.x, inv, p.x + bb.x);
    r.y = fmaf(acc.y, inv, p.y + bb.y);
    r.z = fmaf(acc.z, inv, p.z + bb.z);
    r.w = fmaf(acc.w, inv, p.w + bb.w);
    ((float4*)out)[(size_t)gid * 10 + li] = r;
}

// ---------------------------------------------------------------------------
// Launch. ws layout (int units):
//   deg_i[50048] (memset 0), cursor[50048] (seeded by scanC),
//   row_ptr[50052], blk_sum[256]
//   csr16  ushort[800000] (= 400000 ints)
//   WfA u32[16384], WfB u32[5120]
//   x_bf16 u32[3200000]
//   agg1b u32[50048*64]  -- z2s ushort[50048*40] + p2 f32[50048*40] alias it
//   hb ushort[50048*128]
// ---------------------------------------------------------------------------
extern "C" void kernel_launch(void* const* d_in, const int* in_sizes, int n_in,
                              void* d_out, int out_size, void* d_ws, size_t ws_size,
                              hipStream_t stream) {
    const float* x     = (const float*)d_in[0];
    const int*   ei    = (const int*)d_in[1];
    const float* W1l   = (const float*)d_in[2];
    const float* b1    = (const float*)d_in[3];
    const float* W1r   = (const float*)d_in[4];
    const float* gamma = (const float*)d_in[5];
    const float* beta  = (const float*)d_in[6];
    const float* rmean = (const float*)d_in[7];
    const float* rvar  = (const float*)d_in[8];
    const float* W2l   = (const float*)d_in[9];
    const float* b2    = (const float*)d_in[10];
    const float* W2r   = (const float*)d_in[11];
    float* out = (float*)d_out;

    int* deg_i            = (int*)d_ws;
    int* cursor           = deg_i + 50048;
    int* row_ptr          = cursor + 50048;
    int* blk_sum          = row_ptr + 50052;
    unsigned short* csr16 = (unsigned short*)(blk_sum + 256);
    unsigned* WfA         = (unsigned*)((int*)(blk_sum + 256) + 400000);
    unsigned* WfB         = WfA + 16384;
    unsigned* x_bf16      = WfB + 5120;
    unsigned* agg1b       = x_bf16 + 3200000;
    unsigned short* z2s   = (unsigned short*)agg1b;     // alias (agg1b dead after gemm1)
    float* p2             = (float*)(agg1b + 50048 * 20);
    unsigned short* hb    = (unsigned short*)(agg1b + (size_t)50048 * 64);

    const int* src = ei;
    const int* dst = ei + N_EDGES;

    hipMemsetAsync(deg_i, 0, (size_t)50048 * sizeof(int), stream);

    degprep_kernel<<<DEG_BLOCKS + PREP_BLOCKS, 256, 0, stream>>>(
        dst, deg_i, W1l, W1r, W2l, W2r, x, WfA, WfB, x_bf16);

    scanA_kernel<<<SCAN_BLOCKS, 256, 0, stream>>>(deg_i, row_ptr, blk_sum);
    scanC_kernel<<<SCAN_BLOCKS, 256, 0, stream>>>(row_ptr, cursor, blk_sum);
    fill_kernel<<<EDGE_T / 256, 256, 0, stream>>>(src, dst, cursor, csr16);

    gather1_kernel<<<(N_NODES + 15) / 16, 256, 0, stream>>>(csr16, row_ptr, x_bf16, agg1b);

    gemm1_kernel<<<(N_NODES + 63) / 64, 256, 0, stream>>>(agg1b, x_bf16, WfA, b1, gamma,
                                                          beta, rmean, rvar, hb);

    gemm2_kernel<<<(N_NODES + 63) / 64, 256, 0, stream>>>(hb, WfB, z2s, p2);

    gather2_kernel<<<(N_NODES + 24) / 25, 256, 0, stream>>>(csr16, row_ptr, z2s, p2, b2, out);
}